// Round 5
// baseline (413.734 us; speedup 1.0000x reference)
//
#include <hip/hip_runtime.h>
#include <math.h>
#include <limits.h>

#define NPIX (512*512)
#define NB 16
#define RAD 60
#define DSZ 120

// ---------------- device helpers ----------------

// torch/jax grid_sample semantics: bilinear, zero padding, align_corners=False
__device__ __forceinline__ float gs_bilinear(const float* img, int H, int W,
                                             float gx, float gy) {
    float x = ((gx + 1.0f) * (float)W - 1.0f) * 0.5f;
    float y = ((gy + 1.0f) * (float)H - 1.0f) * 0.5f;
    float xf = floorf(x), yf = floorf(y);
    int ix = (int)xf, iy = (int)yf;
    float wx = x - xf, wy = y - yf;
    float v = 0.0f;
    bool vx0 = (ix >= 0) && (ix < W);
    bool vx1 = (ix >= -1) && (ix < W - 1);
    bool vy0 = (iy >= 0) && (iy < H);
    bool vy1 = (iy >= -1) && (iy < H - 1);
    if (vx0 && vy0) v += img[iy*W + ix]         * ((1.0f - wx) * (1.0f - wy));
    if (vx1 && vy0) v += img[iy*W + ix + 1]     * (wx * (1.0f - wy));
    if (vx0 && vy1) v += img[(iy+1)*W + ix]     * ((1.0f - wx) * wy);
    if (vx1 && vy1) v += img[(iy+1)*W + ix + 1] * (wx * wy);
    return v;
}

// ---------------- kernels ----------------

// inverses + per-call ws init (bbox sentinels, occupancy bitmap zeros)
__global__ void k_prep(const float* __restrict__ sc, const float* __restrict__ rot,
                       const float* __restrict__ tr, float* __restrict__ ws_inv,
                       int* __restrict__ bbox, unsigned* __restrict__ occ) {
    int t = threadIdx.x;
    if (t < 48) {
        int m = t >> 4, b = t & 15;
        const float* th = (m == 0 ? sc : (m == 1 ? rot : tr)) + b * 6;
        float a  = th[0], bb = th[1], tx = th[2];
        float c  = th[3], d  = th[4], ty = th[5];
        float L10 = c / a;
        float dp  = d  - L10 * bb;
        float typ = ty - L10 * tx;
        float i10 = (0.0f - L10) / dp;
        float i00 = (1.0f - bb * i10) / a;
        float i11 = 1.0f / dp;
        float i01 = (0.0f - bb * i11) / a;
        float i12 = (0.0f - typ) / dp;
        float i02 = (0.0f - bb * i12 - tx) / a;
        float* o = ws_inv + m * 96 + b * 6;
        o[0] = i00; o[1] = i01; o[2] = i02;
        o[3] = i10; o[4] = i11; o[5] = i12;
    }
    // bbox[jb*4 + {0:rmin,1:cmin,2:rmax,3:cmax}]
    bbox[t] = ((t & 3) < 2) ? INT_MAX : INT_MIN;
    if (t < 128) occ[t] = 0u;
}

// mask-space occupancy: 1 bit per 16x16 tile per mask (word=tilerow, bit=tilecol)
__global__ void k_occ(const float* __restrict__ masks, unsigned* __restrict__ occ) {
    int tile = blockIdx.x;          // 0..4095
    int j = tile >> 10, t = tile & 1023;
    int ty = t >> 5, tx = t & 31;
    const float* mk = masks + (size_t)j * NPIX;
    int any = 0;
    for (int i = threadIdx.x; i < 256; i += 64) {
        int py = ty * 16 + (i >> 4), px = tx * 16 + (i & 15);
        if (mk[py * 512 + px] != 0.0f) any = 1;
    }
    unsigned long long m = __ballot(any);
    if (threadIdx.x == 0 && m) atomicOr(&occ[j * 32 + ty], 1u << tx);
}

// classify each (jb, output 16x16 tile): can it possibly touch a nonzero mask texel?
// Conservative: corner-exact linear bboxes + 1-texel rounding pad at each stage.
__global__ void __launch_bounds__(256) k_otile(const unsigned* __restrict__ occ,
                                               const float* __restrict__ inv1,
                                               const float* __restrict__ inv2,
                                               unsigned char* __restrict__ otile) {
    int idx = blockIdx.x * 256 + threadIdx.x;   // 0..65535
    int jb = idx >> 10, tile = idx & 1023;
    int j = jb >> 4, b = jb & 15;
    int ty = tile >> 5, tx = tile & 31;
    const float* t1 = inv1 + b * 6;
    const float* t2 = inv2 + b * 6;
    float xs[2] = { (float)(tx * 16), (float)(tx * 16 + 15) };
    float ys[2] = { (float)(ty * 16), (float)(ty * 16 + 15) };
    float sxmin = 1e30f, sxmax = -1e30f, symin = 1e30f, symax = -1e30f;
    for (int cy = 0; cy < 2; ++cy)
        for (int cx = 0; cx < 2; ++cx) {
            float X = (2.0f * xs[cx] + 1.0f) / 512.0f - 1.0f;
            float Y = (2.0f * ys[cy] + 1.0f) / 512.0f - 1.0f;
            float gx = t1[0] * X + t1[1] * Y + t1[2];
            float gy = t1[3] * X + t1[4] * Y + t1[5];
            float sx = ((gx + 1.0f) * 512.0f - 1.0f) * 0.5f;
            float sy = ((gy + 1.0f) * 512.0f - 1.0f) * 0.5f;
            sxmin = fminf(sxmin, sx); sxmax = fmaxf(sxmax, sx);
            symin = fminf(symin, sy); symax = fmaxf(symax, sy);
        }
    // intermediate-space integer tap coords (pad 1 for float rounding)
    int c0 = max((int)floorf(sxmin) - 1, 0), c1 = min((int)floorf(sxmax) + 2, 511);
    int r0 = max((int)floorf(symin) - 1, 0), r1 = min((int)floorf(symax) + 2, 511);
    unsigned char any = 0;
    if (c0 <= c1 && r0 <= r1) {
        float A0 = t2[0], A1 = t2[1], A3 = t2[3], A4 = t2[4];
        float Kx = 0.5f * (-511.0f * (A0 + A1) + 512.0f * t2[2] + 511.0f);
        float Ky = 0.5f * (-511.0f * (A3 + A4) + 512.0f * t2[5] + 511.0f);
        float pxmin = A0 * (A0 >= 0.f ? c0 : c1) + A1 * (A1 >= 0.f ? r0 : r1) + Kx;
        float pxmax = A0 * (A0 >= 0.f ? c1 : c0) + A1 * (A1 >= 0.f ? r1 : r0) + Kx;
        float pymin = A3 * (A3 >= 0.f ? c0 : c1) + A4 * (A4 >= 0.f ? r0 : r1) + Ky;
        float pymax = A3 * (A3 >= 0.f ? c1 : c0) + A4 * (A4 >= 0.f ? r1 : r0) + Ky;
        int xlo = max((int)floorf(pxmin) - 1, 0), xhi = min((int)floorf(pxmax) + 2, 511);
        int ylo = max((int)floorf(pymin) - 1, 0), yhi = min((int)floorf(pymax) + 2, 511);
        if (xlo <= xhi && ylo <= yhi)
            for (int tr = ylo >> 4; tr <= yhi >> 4; ++tr)
                for (int tc = xlo >> 4; tc <= xhi >> 4; ++tc)
                    if ((occ[j * 32 + tr] >> tc) & 1u) any = 1;
    }
    otile[jb * 1024 + tile] = any;
}

// coalesced float4 zero-fill (out3 region)
__global__ void __launch_bounds__(256) k_zero(float4* __restrict__ p, int n4) {
    int stride = gridDim.x * 256;
    for (int i = blockIdx.x * 256 + threadIdx.x; i < n4; i += stride)
        p[i] = make_float4(0.f, 0.f, 0.f, 0.f);
}

// jax.image.resize linear 128->512
__global__ void __launch_bounds__(256) k_upsample(const float* __restrict__ in,
                                                  float* __restrict__ out) {
    int b = blockIdx.y;
    int p = blockIdx.x * 256 + threadIdx.x;
    int y = p >> 9, x = p & 511;
    const float* src = in + b * 128 * 128;
    float sx = (float)x * 0.25f - 0.375f;
    float sy = (float)y * 0.25f - 0.375f;
    float fx0 = floorf(sx), fy0 = floorf(sy);
    int ix = (int)fx0, iy = (int)fy0;
    float fx = sx - fx0, fy = sy - fy0;
    int ix0 = min(max(ix, 0), 127),     ix1 = min(max(ix + 1, 0), 127);
    int iy0 = min(max(iy, 0), 127),     iy1 = min(max(iy + 1, 0), 127);
    float v00 = src[iy0 * 128 + ix0], v10 = src[iy0 * 128 + ix1];
    float v01 = src[iy1 * 128 + ix0], v11 = src[iy1 * 128 + ix1];
    float v = (v00 * (1.0f - fx) + v10 * fx) * (1.0f - fy)
            + (v01 * (1.0f - fx) + v11 * fx) * fy;
    out[(size_t)b * NPIX + p] = v;
}

// one affine grid_sample pass over (B,512,512); optional dual store
__global__ void __launch_bounds__(256) k_gsample(const float* __restrict__ src,
                                                 float* __restrict__ dst,
                                                 float* __restrict__ dst2,
                                                 const float* __restrict__ thetas) {
    int b = blockIdx.y;
    int p = blockIdx.x * 256 + threadIdx.x;
    int y = p >> 9, x = p & 511;
    const float* th = thetas + b * 6;
    float X = (2.0f * (float)x + 1.0f) / 512.0f - 1.0f;
    float Y = (2.0f * (float)y + 1.0f) / 512.0f - 1.0f;
    float gx = th[0] * X + th[1] * Y + th[2];
    float gy = th[3] * X + th[4] * Y + th[5];
    float v = gs_bilinear(src + (size_t)b * NPIX, 512, 512, gx, gy);
    dst[(size_t)b * NPIX + p] = v;
    if (dst2) dst2[(size_t)b * NPIX + p] = v;
}

__device__ __forceinline__ float rm2_val(const float* mk, const float* t2, int cx_, int ry_) {
    float X2 = (2.0f * (float)cx_ + 1.0f) / 512.0f - 1.0f;
    float Y2 = (2.0f * (float)ry_ + 1.0f) / 512.0f - 1.0f;
    float g2x = t2[0] * X2 + t2[1] * Y2 + t2[2];
    float g2y = t2[3] * X2 + t2[4] * Y2 + t2[5];
    return gs_bilinear(mk, 512, 512, g2x, g2y);
}

// fused: rm = gs(gs(mask_j, g2), g1) >= 0.5 on LIVE tiles only (out3 pre-zeroed).
// grid: (1024 tiles, 64 jb), block = one 16x16 output tile. Dead tiles: no store.
__global__ void __launch_bounds__(256) k_mask_live(const float* __restrict__ masks,
                                                   float* __restrict__ out3,
                                                   const float* __restrict__ inv1,
                                                   const float* __restrict__ inv2,
                                                   const unsigned char* __restrict__ otile,
                                                   int* __restrict__ bbox) {
    int jb = blockIdx.y;
    int tile = blockIdx.x;
    if (!otile[jb * 1024 + tile]) return;   // block-uniform: provably all-zero tile

    __shared__ int sbb[4];
    if (threadIdx.x == 0) { sbb[0] = INT_MAX; sbb[1] = INT_MAX; sbb[2] = INT_MIN; sbb[3] = INT_MIN; }
    __syncthreads();

    int ty = tile >> 5, tx = tile & 31;
    int y = ty * 16 + (threadIdx.x >> 4);
    int x = tx * 16 + (threadIdx.x & 15);
    size_t op = (size_t)jb * NPIX + y * 512 + x;

    int j = jb >> 4, b = jb & 15;
    const float* t1 = inv1 + b * 6;
    const float* t2 = inv2 + b * 6;
    const float* mk = masks + (size_t)j * NPIX;

    float X = (2.0f * (float)x + 1.0f) / 512.0f - 1.0f;
    float Y = (2.0f * (float)y + 1.0f) / 512.0f - 1.0f;
    float gx = t1[0] * X + t1[1] * Y + t1[2];
    float gy = t1[3] * X + t1[4] * Y + t1[5];
    float sx = ((gx + 1.0f) * 512.0f - 1.0f) * 0.5f;
    float sy = ((gy + 1.0f) * 512.0f - 1.0f) * 0.5f;
    float xf = floorf(sx), yf = floorf(sy);
    int ix = (int)xf, iy = (int)yf;
    float wx = sx - xf, wy = sy - yf;

    float v = 0.0f;
    bool vx0 = (ix >= 0) && (ix < 512);
    bool vx1 = (ix >= -1) && (ix < 511);
    bool vy0 = (iy >= 0) && (iy < 512);
    bool vy1 = (iy >= -1) && (iy < 511);
    if (vx0 && vy0) v += rm2_val(mk, t2, ix,     iy    ) * ((1.0f - wx) * (1.0f - wy));
    if (vx1 && vy0) v += rm2_val(mk, t2, ix + 1, iy    ) * (wx * (1.0f - wy));
    if (vx0 && vy1) v += rm2_val(mk, t2, ix,     iy + 1) * ((1.0f - wx) * wy);
    if (vx1 && vy1) v += rm2_val(mk, t2, ix + 1, iy + 1) * (wx * wy);

    float res = 0.0f;
    if (v >= 0.5f) {
        res = 1.0f;
        atomicMin(&sbb[0], y); atomicMin(&sbb[1], x);
        atomicMax(&sbb[2], y); atomicMax(&sbb[3], x);
    }
    out3[op] = res;

    __syncthreads();
    if (threadIdx.x == 0 && sbb[2] != INT_MIN) {
        atomicMin(&bbox[jb * 4 + 0], sbb[0]);
        atomicMin(&bbox[jb * 4 + 1], sbb[1]);
        atomicMax(&bbox[jb * 4 + 2], sbb[2]);
        atomicMax(&bbox[jb * 4 + 3], sbb[3]);
    }
}

// fused COM stats: one block per (j,b); phase A -> threshold (LDS), phase B -> crop origin
__global__ void __launch_bounds__(256) k_stats(const float* __restrict__ pred,
                                               const float* __restrict__ mrot,
                                               const int* __restrict__ bbox,
                                               int* __restrict__ xy) {
    int jb = blockIdx.x;
    int b = jb & 15;
    int rmin = bbox[jb*4+0], cmin = bbox[jb*4+1], rmax = bbox[jb*4+2], cmax = bbox[jb*4+3];
    const float* img = pred + (size_t)b * NPIX;
    const float* mk  = mrot + (size_t)jb * NPIX;
    int lane = threadIdx.x & 63, w = threadIdx.x >> 6;
    int W = cmax - cmin + 1;
    int total = (rmax >= rmin) ? W * (rmax - rmin + 1) : 0;

    // phase A: sum(mask), sum(img*mask)
    double msum = 0.0, isum = 0.0;
    for (int i = threadIdx.x; i < total; i += 256) {
        int r = rmin + i / W, c = cmin + i % W;
        float m = mk[r * 512 + c];
        if (m != 0.0f) {
            msum += (double)m;
            isum += (double)(img[r * 512 + c] * m);
        }
    }
    for (int o = 32; o > 0; o >>= 1) {
        msum += __shfl_down(msum, o, 64);
        isum += __shfl_down(isum, o, 64);
    }
    __shared__ double s0[4], s1[4], s2[4];
    __shared__ double sthr;
    if (lane == 0) { s0[w] = msum; s1[w] = isum; }
    __syncthreads();
    if (threadIdx.x == 0) {
        double M = s0[0] + s0[1] + s0[2] + s0[3];
        double I = s1[0] + s1[1] + s1[2] + s1[3];
        sthr = (I / fmax(M, 1.0)) * 1.5;
    }
    __syncthreads();
    double t = sthr;

    // phase B: thresholded weighted centroid
    double wsum = 0.0, sy = 0.0, sx = 0.0;
    for (int i = threadIdx.x; i < total; i += 256) {
        int r = rmin + i / W, c = cmin + i % W;
        float m = mk[r * 512 + c];
        if (m != 0.0f) {
            float v = img[r * 512 + c] * m;
            if ((double)v > t) {
                double vd = (double)v;
                wsum += vd;
                sy += vd * (double)r;   // row (cx in reference)
                sx += vd * (double)c;   // col (cy in reference)
            }
        }
    }
    for (int o = 32; o > 0; o >>= 1) {
        wsum += __shfl_down(wsum, o, 64);
        sy   += __shfl_down(sy,   o, 64);
        sx   += __shfl_down(sx,   o, 64);
    }
    __syncthreads();
    if (lane == 0) { s0[w] = wsum; s1[w] = sy; s2[w] = sx; }
    __syncthreads();
    if (threadIdx.x == 0) {
        double W_ = s0[0] + s0[1] + s0[2] + s0[3];
        double SY = s1[0] + s1[1] + s1[2] + s1[3];
        double SX = s2[0] + s2[1] + s2[2] + s2[3];
        double tot = W_ + 1e-8;
        int x0 = (int)rint(SY / tot) - RAD;
        int y0 = (int)rint(SX / tot) - RAD;
        x0 = min(max(x0, 0), 512 - DSZ);
        y0 = min(max(y0, 0), 512 - DSZ);
        xy[jb * 2 + 0] = x0;
        xy[jb * 2 + 1] = y0;
    }
}

// revise one mask index j across the batch: crop->dot divide->grid_sample->write back
__global__ void __launch_bounds__(256) k_patch(float* __restrict__ img,
                                               const int* __restrict__ xy,
                                               const float* __restrict__ inv1,
                                               const float* __restrict__ adj, int j) {
    __shared__ float patch[DSZ * DSZ];
    int b = blockIdx.x;
    int jb = j * 16 + b;
    int x0 = xy[jb * 2 + 0];   // row start
    int y0 = xy[jb * 2 + 1];   // col start
    float a = adj[b];
    float* im = img + (size_t)b * NPIX;
    for (int t = threadIdx.x; t < DSZ * DSZ; t += 256) {
        int u = t / DSZ, v = t % DSZ;
        float val = im[(x0 + u) * 512 + (y0 + v)];
        int du = u - RAD, dv = v - RAD;
        if (du * du + dv * dv <= 16) val = val / a;
        patch[t] = val;
    }
    __syncthreads();
    const float* th = inv1 + b * 6;
    float t0 = th[0], t1 = th[1], t2 = th[2], t3 = th[3], t4 = th[4], t5 = th[5];
    for (int t = threadIdx.x; t < DSZ * DSZ; t += 256) {
        int py = t / DSZ, px = t % DSZ;
        float X = (2.0f * (float)px + 1.0f) / 120.0f - 1.0f;
        float Y = (2.0f * (float)py + 1.0f) / 120.0f - 1.0f;
        float gx = t0 * X + t1 * Y + t2;
        float gy = t3 * X + t4 * Y + t5;
        float o = gs_bilinear(patch, DSZ, DSZ, gx, gy);
        im[(x0 + py) * 512 + (y0 + px)] = o;
    }
}

// ---------------- launcher ----------------

extern "C" void kernel_launch(void* const* d_in, const int* in_sizes, int n_in,
                              void* d_out, int out_size, void* d_ws, size_t ws_size,
                              hipStream_t stream) {
    const float* base  = (const float*)d_in[0];
    const float* sc    = (const float*)d_in[1];
    const float* rot   = (const float*)d_in[2];
    const float* tr    = (const float*)d_in[3];
    const float* adj   = (const float*)d_in[4];
    const float* masks = (const float*)d_in[5];

    float* out  = (float*)d_out;
    float* out0 = out;                               // base_inp
    float* out1 = out0 + (size_t)NB * NPIX;          // pred_input
    float* out2 = out1 + (size_t)NB * NPIX;          // pred_revise
    float* out3 = out2 + (size_t)NB * NPIX;          // masks_rot (4,16,512,512)

    // ws layout (bytes): inv @0, xy @4096, bbox @8192, occ @12288, otile @16384 (64KB)
    float*         inv1  = (float*)d_ws;
    float*         inv2  = inv1 + 96;
    float*         inv3  = inv1 + 192;
    int*           xy    = (int*)((char*)d_ws + 4096);
    int*           bbox  = (int*)((char*)d_ws + 8192);
    unsigned*      occ   = (unsigned*)((char*)d_ws + 12288);
    unsigned char* otile = (unsigned char*)((char*)d_ws + 16384);

    dim3 gridImg(NPIX / 256, NB);

    k_prep<<<1, 256, 0, stream>>>(sc, rot, tr, (float*)d_ws, bbox, occ);
    k_occ<<<4096, 64, 0, stream>>>(masks, occ);
    k_otile<<<256, 256, 0, stream>>>(occ, inv1, inv2, otile);
    k_upsample<<<gridImg, 256, 0, stream>>>(base, out0);

    // image chain: base_inp -g3-> tmpA(out2) -g2-> tmpB(out3[:16]) -g1-> out1 (+out2 copy)
    k_gsample<<<gridImg, 256, 0, stream>>>(out0, out2, nullptr, inv3);
    k_gsample<<<gridImg, 256, 0, stream>>>(out2, out3, nullptr, inv2);
    k_gsample<<<gridImg, 256, 0, stream>>>(out3, out1, out2, inv1);  // dual store

    // masks: zero-fill (coalesced) then compute live tiles only
    k_zero<<<2048, 256, 0, stream>>>((float4*)out3, 64 * NPIX / 4);
    k_mask_live<<<dim3(1024, 64), 256, 0, stream>>>(masks, out3, inv1, inv2, otile, bbox);

    // fused COM stats over per-(j,b) bounding boxes
    k_stats<<<64, 256, 0, stream>>>(out1, out3, bbox, xy);

    // sequential over j: matches reference update order (patches may overlap across j)
    for (int j = 0; j < 4; ++j)
        k_patch<<<NB, 256, 0, stream>>>(out2, xy, inv1, adj, j);
}

// Round 6
// 381.931 us; speedup vs baseline: 1.0833x; 1.0833x over previous
//
#include <hip/hip_runtime.h>
#include <math.h>
#include <limits.h>

#define NPIX (512*512)
#define NB 16
#define RAD 60
#define DSZ 120

// ---------------- device helpers ----------------

// torch/jax grid_sample semantics: bilinear, zero padding, align_corners=False
__device__ __forceinline__ float gs_bilinear(const float* img, int H, int W,
                                             float gx, float gy) {
    float x = ((gx + 1.0f) * (float)W - 1.0f) * 0.5f;
    float y = ((gy + 1.0f) * (float)H - 1.0f) * 0.5f;
    float xf = floorf(x), yf = floorf(y);
    int ix = (int)xf, iy = (int)yf;
    float wx = x - xf, wy = y - yf;
    float v = 0.0f;
    bool vx0 = (ix >= 0) && (ix < W);
    bool vx1 = (ix >= -1) && (ix < W - 1);
    bool vy0 = (iy >= 0) && (iy < H);
    bool vy1 = (iy >= -1) && (iy < H - 1);
    if (vx0 && vy0) v += img[iy*W + ix]         * ((1.0f - wx) * (1.0f - wy));
    if (vx1 && vy0) v += img[iy*W + ix + 1]     * (wx * (1.0f - wy));
    if (vx0 && vy1) v += img[(iy+1)*W + ix]     * ((1.0f - wx) * wy);
    if (vx1 && vy1) v += img[(iy+1)*W + ix + 1] * (wx * wy);
    return v;
}

// ---------------- kernels ----------------

// inverses + per-call ws init (bbox sentinels, occ zeros, queue counter)
__global__ void k_prep(const float* __restrict__ sc, const float* __restrict__ rot,
                       const float* __restrict__ tr, float* __restrict__ ws_inv,
                       int* __restrict__ bbox, unsigned* __restrict__ occ,
                       int* __restrict__ qcount) {
    int t = threadIdx.x;
    if (t < 48) {
        int m = t >> 4, b = t & 15;
        const float* th = (m == 0 ? sc : (m == 1 ? rot : tr)) + b * 6;
        float a  = th[0], bb = th[1], tx = th[2];
        float c  = th[3], d  = th[4], ty = th[5];
        float L10 = c / a;
        float dp  = d  - L10 * bb;
        float typ = ty - L10 * tx;
        float i10 = (0.0f - L10) / dp;
        float i00 = (1.0f - bb * i10) / a;
        float i11 = 1.0f / dp;
        float i01 = (0.0f - bb * i11) / a;
        float i12 = (0.0f - typ) / dp;
        float i02 = (0.0f - bb * i12 - tx) / a;
        float* o = ws_inv + m * 96 + b * 6;
        o[0] = i00; o[1] = i01; o[2] = i02;
        o[3] = i10; o[4] = i11; o[5] = i12;
    }
    // bbox[jb*4 + {0:rmin,1:cmin,2:rmax,3:cmax}]
    bbox[t] = ((t & 3) < 2) ? INT_MAX : INT_MIN;
    if (t < 128) occ[t] = 0u;
    if (t == 0) *qcount = 0;
}

// mask-space occupancy: 1 bit per 16x16 tile per mask. 4 tiles/block (1 wave each).
__global__ void __launch_bounds__(256) k_occ(const float* __restrict__ masks,
                                             unsigned* __restrict__ occ) {
    int tile = blockIdx.x * 4 + (threadIdx.x >> 6);  // 0..4095
    int lane = threadIdx.x & 63;
    int j = tile >> 10, t = tile & 1023;
    int ty = t >> 5, tx = t & 31;
    const float* mk = masks + (size_t)j * NPIX;
    int any = 0;
    for (int i = lane; i < 256; i += 64) {
        int py = ty * 16 + (i >> 4), px = tx * 16 + (i & 15);
        if (mk[py * 512 + px] != 0.0f) any = 1;
    }
    unsigned long long m = __ballot(any);
    if (lane == 0 && m) atomicOr(&occ[j * 32 + ty], 1u << tx);
}

// classify each (jb, output 16x16 tile); live tiles -> work queue.
// Conservative: corner-exact linear bboxes + 1-texel rounding pad at each stage.
__global__ void __launch_bounds__(256) k_otile(const unsigned* __restrict__ occ,
                                               const float* __restrict__ inv1,
                                               const float* __restrict__ inv2,
                                               int* __restrict__ queue,
                                               int* __restrict__ qcount) {
    int idx = blockIdx.x * 256 + threadIdx.x;   // 0..65535
    int jb = idx >> 10, tile = idx & 1023;
    int j = jb >> 4, b = jb & 15;
    int ty = tile >> 5, tx = tile & 31;
    const float* t1 = inv1 + b * 6;
    const float* t2 = inv2 + b * 6;
    float xs[2] = { (float)(tx * 16), (float)(tx * 16 + 15) };
    float ys[2] = { (float)(ty * 16), (float)(ty * 16 + 15) };
    float sxmin = 1e30f, sxmax = -1e30f, symin = 1e30f, symax = -1e30f;
    for (int cy = 0; cy < 2; ++cy)
        for (int cx = 0; cx < 2; ++cx) {
            float X = (2.0f * xs[cx] + 1.0f) / 512.0f - 1.0f;
            float Y = (2.0f * ys[cy] + 1.0f) / 512.0f - 1.0f;
            float gx = t1[0] * X + t1[1] * Y + t1[2];
            float gy = t1[3] * X + t1[4] * Y + t1[5];
            float sx = ((gx + 1.0f) * 512.0f - 1.0f) * 0.5f;
            float sy = ((gy + 1.0f) * 512.0f - 1.0f) * 0.5f;
            sxmin = fminf(sxmin, sx); sxmax = fmaxf(sxmax, sx);
            symin = fminf(symin, sy); symax = fmaxf(symax, sy);
        }
    int c0 = max((int)floorf(sxmin) - 1, 0), c1 = min((int)floorf(sxmax) + 2, 511);
    int r0 = max((int)floorf(symin) - 1, 0), r1 = min((int)floorf(symax) + 2, 511);
    bool any = false;
    if (c0 <= c1 && r0 <= r1) {
        float A0 = t2[0], A1 = t2[1], A3 = t2[3], A4 = t2[4];
        float Kx = 0.5f * (-511.0f * (A0 + A1) + 512.0f * t2[2] + 511.0f);
        float Ky = 0.5f * (-511.0f * (A3 + A4) + 512.0f * t2[5] + 511.0f);
        float pxmin = A0 * (A0 >= 0.f ? c0 : c1) + A1 * (A1 >= 0.f ? r0 : r1) + Kx;
        float pxmax = A0 * (A0 >= 0.f ? c1 : c0) + A1 * (A1 >= 0.f ? r1 : r0) + Kx;
        float pymin = A3 * (A3 >= 0.f ? c0 : c1) + A4 * (A4 >= 0.f ? r0 : r1) + Ky;
        float pymax = A3 * (A3 >= 0.f ? c1 : c0) + A4 * (A4 >= 0.f ? r1 : r0) + Ky;
        int xlo = max((int)floorf(pxmin) - 1, 0), xhi = min((int)floorf(pxmax) + 2, 511);
        int ylo = max((int)floorf(pymin) - 1, 0), yhi = min((int)floorf(pymax) + 2, 511);
        if (xlo <= xhi && ylo <= yhi)
            for (int tr = ylo >> 4; tr <= yhi >> 4; ++tr)
                for (int tc = xlo >> 4; tc <= xhi >> 4; ++tc)
                    if ((occ[j * 32 + tr] >> tc) & 1u) any = true;
    }
    if (any) {
        int pos = atomicAdd(qcount, 1);
        queue[pos] = (jb << 10) | tile;   // disjoint writes; order irrelevant
    }
}

// coalesced float4 zero-fill (out3 region)
__global__ void __launch_bounds__(256) k_zero(float4* __restrict__ p, int n4) {
    int stride = gridDim.x * 256;
    for (int i = blockIdx.x * 256 + threadIdx.x; i < n4; i += stride)
        p[i] = make_float4(0.f, 0.f, 0.f, 0.f);
}

// jax.image.resize linear 128->512; 4 px per thread, float4 store
__global__ void __launch_bounds__(256) k_upsample(const float* __restrict__ in,
                                                  float* __restrict__ out) {
    int b = blockIdx.y;
    int p4 = blockIdx.x * 256 + threadIdx.x;      // 0..65535
    int p = p4 * 4;
    int y = p >> 9, x0p = p & 511;
    const float* src = in + b * 128 * 128;
    float r[4];
    float sy = (float)y * 0.25f - 0.375f;
    float fy0 = floorf(sy);
    int iy = (int)fy0;
    float fy = sy - fy0;
    int iy0 = min(max(iy, 0), 127), iy1 = min(max(iy + 1, 0), 127);
    #pragma unroll
    for (int k = 0; k < 4; ++k) {
        int x = x0p + k;
        float sx = (float)x * 0.25f - 0.375f;
        float fx0 = floorf(sx);
        int ix = (int)fx0;
        float fx = sx - fx0;
        int ix0 = min(max(ix, 0), 127), ix1 = min(max(ix + 1, 0), 127);
        float v00 = src[iy0 * 128 + ix0], v10 = src[iy0 * 128 + ix1];
        float v01 = src[iy1 * 128 + ix0], v11 = src[iy1 * 128 + ix1];
        r[k] = (v00 * (1.0f - fx) + v10 * fx) * (1.0f - fy)
             + (v01 * (1.0f - fx) + v11 * fx) * fy;
    }
    *(float4*)(out + (size_t)b * NPIX + p) = make_float4(r[0], r[1], r[2], r[3]);
}

// one affine grid_sample pass; 4 px per thread, float4 store; optional dual store
__global__ void __launch_bounds__(256) k_gsample(const float* __restrict__ src,
                                                 float* __restrict__ dst,
                                                 float* __restrict__ dst2,
                                                 const float* __restrict__ thetas) {
    int b = blockIdx.y;
    int p4 = blockIdx.x * 256 + threadIdx.x;
    int p = p4 * 4;
    int y = p >> 9, x0p = p & 511;
    const float* th = thetas + b * 6;
    const float* im = src + (size_t)b * NPIX;
    float t0 = th[0], t1 = th[1], t2 = th[2], t3 = th[3], t4 = th[4], t5 = th[5];
    float Y = (2.0f * (float)y + 1.0f) / 512.0f - 1.0f;
    float r[4];
    #pragma unroll
    for (int k = 0; k < 4; ++k) {
        float X = (2.0f * (float)(x0p + k) + 1.0f) / 512.0f - 1.0f;
        float gx = t0 * X + t1 * Y + t2;
        float gy = t3 * X + t4 * Y + t5;
        r[k] = gs_bilinear(im, 512, 512, gx, gy);
    }
    float4 v4 = make_float4(r[0], r[1], r[2], r[3]);
    *(float4*)(dst + (size_t)b * NPIX + p) = v4;
    if (dst2) *(float4*)(dst2 + (size_t)b * NPIX + p) = v4;
}

__device__ __forceinline__ float rm2_val(const float* mk, const float* t2, int cx_, int ry_) {
    float X2 = (2.0f * (float)cx_ + 1.0f) / 512.0f - 1.0f;
    float Y2 = (2.0f * (float)ry_ + 1.0f) / 512.0f - 1.0f;
    float g2x = t2[0] * X2 + t2[1] * Y2 + t2[2];
    float g2y = t2[3] * X2 + t2[4] * Y2 + t2[5];
    return gs_bilinear(mk, 512, 512, g2x, g2y);
}

// queue consumer: rm = gs(gs(mask_j, g2), g1) >= 0.5 on live tiles (out3 pre-zeroed)
__global__ void __launch_bounds__(256) k_mask_live(const float* __restrict__ masks,
                                                   float* __restrict__ out3,
                                                   const float* __restrict__ inv1,
                                                   const float* __restrict__ inv2,
                                                   const int* __restrict__ queue,
                                                   const int* __restrict__ qcount,
                                                   int* __restrict__ bbox) {
    __shared__ int sbb[4];
    int n = *qcount;
    for (int q = blockIdx.x; q < n; q += gridDim.x) {
        int e = queue[q];
        int jb = e >> 10, tile = e & 1023;
        if (threadIdx.x == 0) { sbb[0] = INT_MAX; sbb[1] = INT_MAX; sbb[2] = INT_MIN; sbb[3] = INT_MIN; }
        __syncthreads();

        int ty = tile >> 5, tx = tile & 31;
        int y = ty * 16 + (threadIdx.x >> 4);
        int x = tx * 16 + (threadIdx.x & 15);
        int j = jb >> 4, b = jb & 15;
        const float* t1 = inv1 + b * 6;
        const float* t2 = inv2 + b * 6;
        const float* mk = masks + (size_t)j * NPIX;

        float X = (2.0f * (float)x + 1.0f) / 512.0f - 1.0f;
        float Y = (2.0f * (float)y + 1.0f) / 512.0f - 1.0f;
        float gx = t1[0] * X + t1[1] * Y + t1[2];
        float gy = t1[3] * X + t1[4] * Y + t1[5];
        float sx = ((gx + 1.0f) * 512.0f - 1.0f) * 0.5f;
        float sy = ((gy + 1.0f) * 512.0f - 1.0f) * 0.5f;
        float xf = floorf(sx), yf = floorf(sy);
        int ix = (int)xf, iy = (int)yf;
        float wx = sx - xf, wy = sy - yf;

        float v = 0.0f;
        bool vx0 = (ix >= 0) && (ix < 512);
        bool vx1 = (ix >= -1) && (ix < 511);
        bool vy0 = (iy >= 0) && (iy < 512);
        bool vy1 = (iy >= -1) && (iy < 511);
        if (vx0 && vy0) v += rm2_val(mk, t2, ix,     iy    ) * ((1.0f - wx) * (1.0f - wy));
        if (vx1 && vy0) v += rm2_val(mk, t2, ix + 1, iy    ) * (wx * (1.0f - wy));
        if (vx0 && vy1) v += rm2_val(mk, t2, ix,     iy + 1) * ((1.0f - wx) * wy);
        if (vx1 && vy1) v += rm2_val(mk, t2, ix + 1, iy + 1) * (wx * wy);

        float res = 0.0f;
        if (v >= 0.5f) {
            res = 1.0f;
            atomicMin(&sbb[0], y); atomicMin(&sbb[1], x);
            atomicMax(&sbb[2], y); atomicMax(&sbb[3], x);
        }
        out3[(size_t)jb * NPIX + y * 512 + x] = res;

        __syncthreads();
        if (threadIdx.x == 0 && sbb[2] != INT_MIN) {
            atomicMin(&bbox[jb * 4 + 0], sbb[0]);
            atomicMin(&bbox[jb * 4 + 1], sbb[1]);
            atomicMax(&bbox[jb * 4 + 2], sbb[2]);
            atomicMax(&bbox[jb * 4 + 3], sbb[3]);
        }
        __syncthreads();
    }
}

// fused COM stats: one block per (j,b); phase A -> threshold (LDS), phase B -> crop origin
__global__ void __launch_bounds__(256) k_stats(const float* __restrict__ pred,
                                               const float* __restrict__ mrot,
                                               const int* __restrict__ bbox,
                                               int* __restrict__ xy) {
    int jb = blockIdx.x;
    int b = jb & 15;
    int rmin = bbox[jb*4+0], cmin = bbox[jb*4+1], rmax = bbox[jb*4+2], cmax = bbox[jb*4+3];
    const float* img = pred + (size_t)b * NPIX;
    const float* mk  = mrot + (size_t)jb * NPIX;
    int lane = threadIdx.x & 63, w = threadIdx.x >> 6;
    int W = cmax - cmin + 1;
    int total = (rmax >= rmin) ? W * (rmax - rmin + 1) : 0;

    // phase A: sum(mask), sum(img*mask)
    double msum = 0.0, isum = 0.0;
    for (int i = threadIdx.x; i < total; i += 256) {
        int r = rmin + i / W, c = cmin + i % W;
        float m = mk[r * 512 + c];
        if (m != 0.0f) {
            msum += (double)m;
            isum += (double)(img[r * 512 + c] * m);
        }
    }
    for (int o = 32; o > 0; o >>= 1) {
        msum += __shfl_down(msum, o, 64);
        isum += __shfl_down(isum, o, 64);
    }
    __shared__ double s0[4], s1[4], s2[4];
    __shared__ double sthr;
    if (lane == 0) { s0[w] = msum; s1[w] = isum; }
    __syncthreads();
    if (threadIdx.x == 0) {
        double M = s0[0] + s0[1] + s0[2] + s0[3];
        double I = s1[0] + s1[1] + s1[2] + s1[3];
        sthr = (I / fmax(M, 1.0)) * 1.5;
    }
    __syncthreads();
    double t = sthr;

    // phase B: thresholded weighted centroid
    double wsum = 0.0, sy = 0.0, sx = 0.0;
    for (int i = threadIdx.x; i < total; i += 256) {
        int r = rmin + i / W, c = cmin + i % W;
        float m = mk[r * 512 + c];
        if (m != 0.0f) {
            float v = img[r * 512 + c] * m;
            if ((double)v > t) {
                double vd = (double)v;
                wsum += vd;
                sy += vd * (double)r;   // row (cx in reference)
                sx += vd * (double)c;   // col (cy in reference)
            }
        }
    }
    for (int o = 32; o > 0; o >>= 1) {
        wsum += __shfl_down(wsum, o, 64);
        sy   += __shfl_down(sy,   o, 64);
        sx   += __shfl_down(sx,   o, 64);
    }
    __syncthreads();
    if (lane == 0) { s0[w] = wsum; s1[w] = sy; s2[w] = sx; }
    __syncthreads();
    if (threadIdx.x == 0) {
        double W_ = s0[0] + s0[1] + s0[2] + s0[3];
        double SY = s1[0] + s1[1] + s1[2] + s1[3];
        double SX = s2[0] + s2[1] + s2[2] + s2[3];
        double tot = W_ + 1e-8;
        int x0 = (int)rint(SY / tot) - RAD;
        int y0 = (int)rint(SX / tot) - RAD;
        x0 = min(max(x0, 0), 512 - DSZ);
        y0 = min(max(y0, 0), 512 - DSZ);
        xy[jb * 2 + 0] = x0;
        xy[jb * 2 + 1] = y0;
    }
}

// revise: one block per batch item, loop j=0..3 sequentially (matches reference order;
// same-b overlapping crops serialized by __syncthreads; different b never overlap)
__global__ void __launch_bounds__(256) k_patch(float* __restrict__ img,
                                               const int* __restrict__ xy,
                                               const float* __restrict__ inv1,
                                               const float* __restrict__ adj) {
    __shared__ float patch[DSZ * DSZ];
    int b = blockIdx.x;
    float a = adj[b];
    float* im = img + (size_t)b * NPIX;
    const float* th = inv1 + b * 6;
    float t0 = th[0], t1 = th[1], t2 = th[2], t3 = th[3], t4 = th[4], t5 = th[5];

    for (int j = 0; j < 4; ++j) {
        int jb = j * 16 + b;
        int x0 = xy[jb * 2 + 0];   // row start
        int y0 = xy[jb * 2 + 1];   // col start
        for (int t = threadIdx.x; t < DSZ * DSZ; t += 256) {
            int u = t / DSZ, v = t % DSZ;
            float val = im[(x0 + u) * 512 + (y0 + v)];
            int du = u - RAD, dv = v - RAD;
            if (du * du + dv * dv <= 16) val = val / a;
            patch[t] = val;
        }
        __syncthreads();
        for (int t = threadIdx.x; t < DSZ * DSZ; t += 256) {
            int py = t / DSZ, px = t % DSZ;
            float X = (2.0f * (float)px + 1.0f) / 120.0f - 1.0f;
            float Y = (2.0f * (float)py + 1.0f) / 120.0f - 1.0f;
            float gx = t0 * X + t1 * Y + t2;
            float gy = t3 * X + t4 * Y + t5;
            float o = gs_bilinear(patch, DSZ, DSZ, gx, gy);
            im[(x0 + py) * 512 + (y0 + px)] = o;
        }
        __threadfence_block();
        __syncthreads();
    }
}

// ---------------- launcher ----------------

extern "C" void kernel_launch(void* const* d_in, const int* in_sizes, int n_in,
                              void* d_out, int out_size, void* d_ws, size_t ws_size,
                              hipStream_t stream) {
    const float* base  = (const float*)d_in[0];
    const float* sc    = (const float*)d_in[1];
    const float* rot   = (const float*)d_in[2];
    const float* tr    = (const float*)d_in[3];
    const float* adj   = (const float*)d_in[4];
    const float* masks = (const float*)d_in[5];

    float* out  = (float*)d_out;
    float* out0 = out;                               // base_inp
    float* out1 = out0 + (size_t)NB * NPIX;          // pred_input
    float* out2 = out1 + (size_t)NB * NPIX;          // pred_revise
    float* out3 = out2 + (size_t)NB * NPIX;          // masks_rot (4,16,512,512)

    // ws layout (bytes): inv @0, xy @4096, bbox @8192, occ @12288,
    //                    qcount @16128, queue @16384 (256 KB)
    float*    inv1   = (float*)d_ws;
    float*    inv2   = inv1 + 96;
    float*    inv3   = inv1 + 192;
    int*      xy     = (int*)((char*)d_ws + 4096);
    int*      bbox   = (int*)((char*)d_ws + 8192);
    unsigned* occ    = (unsigned*)((char*)d_ws + 12288);
    int*      qcount = (int*)((char*)d_ws + 16128);
    int*      queue  = (int*)((char*)d_ws + 16384);

    dim3 gridImg4(256, NB);   // 4 px/thread kernels

    k_prep<<<1, 256, 0, stream>>>(sc, rot, tr, (float*)d_ws, bbox, occ, qcount);
    k_occ<<<1024, 256, 0, stream>>>(masks, occ);
    k_otile<<<256, 256, 0, stream>>>(occ, inv1, inv2, queue, qcount);
    k_upsample<<<gridImg4, 256, 0, stream>>>(base, out0);

    // image chain: base_inp -g3-> tmpA(out2) -g2-> tmpB(out3[:16]) -g1-> out1 (+out2 copy)
    k_gsample<<<gridImg4, 256, 0, stream>>>(out0, out2, nullptr, inv3);
    k_gsample<<<gridImg4, 256, 0, stream>>>(out2, out3, nullptr, inv2);
    k_gsample<<<gridImg4, 256, 0, stream>>>(out3, out1, out2, inv1);  // dual store

    // masks: zero-fill (coalesced) then compute live tiles from the queue
    k_zero<<<2048, 256, 0, stream>>>((float4*)out3, 64 * NPIX / 4);
    k_mask_live<<<1024, 256, 0, stream>>>(masks, out3, inv1, inv2, queue, qcount, bbox);

    // fused COM stats over per-(j,b) bounding boxes
    k_stats<<<64, 256, 0, stream>>>(out1, out3, bbox, xy);

    // revise: single launch, j-loop inside
    k_patch<<<NB, 256, 0, stream>>>(out2, xy, inv1, adj);
}

// Round 7
// 278.478 us; speedup vs baseline: 1.4857x; 1.3715x over previous
//
#include <hip/hip_runtime.h>
#include <math.h>
#include <limits.h>

#define NPIX (512*512)
#define NB 16
#define RAD 60
#define DSZ 120
#define PSTR 121   // padded LDS stride (bank-conflict break)

// ---------------- device helpers ----------------

// torch/jax grid_sample semantics: bilinear, zero padding, align_corners=False
__device__ __forceinline__ float gs_bilinear(const float* img, int H, int W,
                                             float gx, float gy) {
    float x = ((gx + 1.0f) * (float)W - 1.0f) * 0.5f;
    float y = ((gy + 1.0f) * (float)H - 1.0f) * 0.5f;
    float xf = floorf(x), yf = floorf(y);
    int ix = (int)xf, iy = (int)yf;
    float wx = x - xf, wy = y - yf;
    float v = 0.0f;
    bool vx0 = (ix >= 0) && (ix < W);
    bool vx1 = (ix >= -1) && (ix < W - 1);
    bool vy0 = (iy >= 0) && (iy < H);
    bool vy1 = (iy >= -1) && (iy < H - 1);
    if (vx0 && vy0) v += img[iy*W + ix]         * ((1.0f - wx) * (1.0f - wy));
    if (vx1 && vy0) v += img[iy*W + ix + 1]     * (wx * (1.0f - wy));
    if (vx0 && vy1) v += img[(iy+1)*W + ix]     * ((1.0f - wx) * wy);
    if (vx1 && vy1) v += img[(iy+1)*W + ix + 1] * (wx * wy);
    return v;
}

// same semantics but LDS patch with padded row stride PSTR, logical 120x120
__device__ __forceinline__ float gs_bilinear_patch(const float* img, float gx, float gy) {
    float x = ((gx + 1.0f) * 120.0f - 1.0f) * 0.5f;
    float y = ((gy + 1.0f) * 120.0f - 1.0f) * 0.5f;
    float xf = floorf(x), yf = floorf(y);
    int ix = (int)xf, iy = (int)yf;
    float wx = x - xf, wy = y - yf;
    float v = 0.0f;
    bool vx0 = (ix >= 0) && (ix < 120);
    bool vx1 = (ix >= -1) && (ix < 119);
    bool vy0 = (iy >= 0) && (iy < 120);
    bool vy1 = (iy >= -1) && (iy < 119);
    if (vx0 && vy0) v += img[iy*PSTR + ix]         * ((1.0f - wx) * (1.0f - wy));
    if (vx1 && vy0) v += img[iy*PSTR + ix + 1]     * (wx * (1.0f - wy));
    if (vx0 && vy1) v += img[(iy+1)*PSTR + ix]     * ((1.0f - wx) * wy);
    if (vx1 && vy1) v += img[(iy+1)*PSTR + ix + 1] * (wx * wy);
    return v;
}

// ---------------- kernels ----------------

// inverses + per-call ws init (bbox sentinels, occ zeros, queue counter)
__global__ void k_prep(const float* __restrict__ sc, const float* __restrict__ rot,
                       const float* __restrict__ tr, float* __restrict__ ws_inv,
                       int* __restrict__ bbox, unsigned* __restrict__ occ,
                       int* __restrict__ qcount) {
    int t = threadIdx.x;
    if (t < 48) {
        int m = t >> 4, b = t & 15;
        const float* th = (m == 0 ? sc : (m == 1 ? rot : tr)) + b * 6;
        float a  = th[0], bb = th[1], tx = th[2];
        float c  = th[3], d  = th[4], ty = th[5];
        float L10 = c / a;
        float dp  = d  - L10 * bb;
        float typ = ty - L10 * tx;
        float i10 = (0.0f - L10) / dp;
        float i00 = (1.0f - bb * i10) / a;
        float i11 = 1.0f / dp;
        float i01 = (0.0f - bb * i11) / a;
        float i12 = (0.0f - typ) / dp;
        float i02 = (0.0f - bb * i12 - tx) / a;
        float* o = ws_inv + m * 96 + b * 6;
        o[0] = i00; o[1] = i01; o[2] = i02;
        o[3] = i10; o[4] = i11; o[5] = i12;
    }
    // bbox[jb*4 + {0:rmin,1:cmin,2:rmax,3:cmax}]
    bbox[t] = ((t & 3) < 2) ? INT_MAX : INT_MIN;
    if (t < 128) occ[t] = 0u;
    if (t == 0) *qcount = 0;
}

// mask-space occupancy: 1 bit per 16x16 tile per mask. 4 tiles/block (1 wave each).
__global__ void __launch_bounds__(256) k_occ(const float* __restrict__ masks,
                                             unsigned* __restrict__ occ) {
    int tile = blockIdx.x * 4 + (threadIdx.x >> 6);  // 0..4095
    int lane = threadIdx.x & 63;
    int j = tile >> 10, t = tile & 1023;
    int ty = t >> 5, tx = t & 31;
    const float* mk = masks + (size_t)j * NPIX;
    int any = 0;
    for (int i = lane; i < 256; i += 64) {
        int py = ty * 16 + (i >> 4), px = tx * 16 + (i & 15);
        if (mk[py * 512 + px] != 0.0f) any = 1;
    }
    unsigned long long m = __ballot(any);
    if (lane == 0 && m) atomicOr(&occ[j * 32 + ty], 1u << tx);
}

// classify each (jb, output 16x16 tile); live tiles -> work queue.
__global__ void __launch_bounds__(256) k_otile(const unsigned* __restrict__ occ,
                                               const float* __restrict__ inv1,
                                               const float* __restrict__ inv2,
                                               int* __restrict__ queue,
                                               int* __restrict__ qcount) {
    int idx = blockIdx.x * 256 + threadIdx.x;   // 0..65535
    int jb = idx >> 10, tile = idx & 1023;
    int j = jb >> 4, b = jb & 15;
    int ty = tile >> 5, tx = tile & 31;
    const float* t1 = inv1 + b * 6;
    const float* t2 = inv2 + b * 6;
    float xs[2] = { (float)(tx * 16), (float)(tx * 16 + 15) };
    float ys[2] = { (float)(ty * 16), (float)(ty * 16 + 15) };
    float sxmin = 1e30f, sxmax = -1e30f, symin = 1e30f, symax = -1e30f;
    for (int cy = 0; cy < 2; ++cy)
        for (int cx = 0; cx < 2; ++cx) {
            float X = (2.0f * xs[cx] + 1.0f) / 512.0f - 1.0f;
            float Y = (2.0f * ys[cy] + 1.0f) / 512.0f - 1.0f;
            float gx = t1[0] * X + t1[1] * Y + t1[2];
            float gy = t1[3] * X + t1[4] * Y + t1[5];
            float sx = ((gx + 1.0f) * 512.0f - 1.0f) * 0.5f;
            float sy = ((gy + 1.0f) * 512.0f - 1.0f) * 0.5f;
            sxmin = fminf(sxmin, sx); sxmax = fmaxf(sxmax, sx);
            symin = fminf(symin, sy); symax = fmaxf(symax, sy);
        }
    int c0 = max((int)floorf(sxmin) - 1, 0), c1 = min((int)floorf(sxmax) + 2, 511);
    int r0 = max((int)floorf(symin) - 1, 0), r1 = min((int)floorf(symax) + 2, 511);
    bool any = false;
    if (c0 <= c1 && r0 <= r1) {
        float A0 = t2[0], A1 = t2[1], A3 = t2[3], A4 = t2[4];
        float Kx = 0.5f * (-511.0f * (A0 + A1) + 512.0f * t2[2] + 511.0f);
        float Ky = 0.5f * (-511.0f * (A3 + A4) + 512.0f * t2[5] + 511.0f);
        float pxmin = A0 * (A0 >= 0.f ? c0 : c1) + A1 * (A1 >= 0.f ? r0 : r1) + Kx;
        float pxmax = A0 * (A0 >= 0.f ? c1 : c0) + A1 * (A1 >= 0.f ? r1 : r0) + Kx;
        float pymin = A3 * (A3 >= 0.f ? c0 : c1) + A4 * (A4 >= 0.f ? r0 : r1) + Ky;
        float pymax = A3 * (A3 >= 0.f ? c1 : c0) + A4 * (A4 >= 0.f ? r1 : r0) + Ky;
        int xlo = max((int)floorf(pxmin) - 1, 0), xhi = min((int)floorf(pxmax) + 2, 511);
        int ylo = max((int)floorf(pymin) - 1, 0), yhi = min((int)floorf(pymax) + 2, 511);
        if (xlo <= xhi && ylo <= yhi)
            for (int tr = ylo >> 4; tr <= yhi >> 4; ++tr)
                for (int tc = xlo >> 4; tc <= xhi >> 4; ++tc)
                    if ((occ[j * 32 + tr] >> tc) & 1u) any = true;
    }
    if (any) {
        int pos = atomicAdd(qcount, 1);
        queue[pos] = (jb << 10) | tile;   // disjoint writes; order irrelevant
    }
}

// coalesced float4 zero-fill (out3 region)
__global__ void __launch_bounds__(256) k_zero(float4* __restrict__ p, int n4) {
    int stride = gridDim.x * 256;
    for (int i = blockIdx.x * 256 + threadIdx.x; i < n4; i += stride)
        p[i] = make_float4(0.f, 0.f, 0.f, 0.f);
}

// jax.image.resize linear 128->512; 4 px per thread, float4 store
__global__ void __launch_bounds__(256) k_upsample(const float* __restrict__ in,
                                                  float* __restrict__ out) {
    int b = blockIdx.y;
    int p4 = blockIdx.x * 256 + threadIdx.x;      // 0..65535
    int p = p4 * 4;
    int y = p >> 9, x0p = p & 511;
    const float* src = in + b * 128 * 128;
    float r[4];
    float sy = (float)y * 0.25f - 0.375f;
    float fy0 = floorf(sy);
    int iy = (int)fy0;
    float fy = sy - fy0;
    int iy0 = min(max(iy, 0), 127), iy1 = min(max(iy + 1, 0), 127);
    #pragma unroll
    for (int k = 0; k < 4; ++k) {
        int x = x0p + k;
        float sx = (float)x * 0.25f - 0.375f;
        float fx0 = floorf(sx);
        int ix = (int)fx0;
        float fx = sx - fx0;
        int ix0 = min(max(ix, 0), 127), ix1 = min(max(ix + 1, 0), 127);
        float v00 = src[iy0 * 128 + ix0], v10 = src[iy0 * 128 + ix1];
        float v01 = src[iy1 * 128 + ix0], v11 = src[iy1 * 128 + ix1];
        r[k] = (v00 * (1.0f - fx) + v10 * fx) * (1.0f - fy)
             + (v01 * (1.0f - fx) + v11 * fx) * fy;
    }
    *(float4*)(out + (size_t)b * NPIX + p) = make_float4(r[0], r[1], r[2], r[3]);
}

// one affine grid_sample pass; 4 px per thread, float4 store; optional dual store
__global__ void __launch_bounds__(256) k_gsample(const float* __restrict__ src,
                                                 float* __restrict__ dst,
                                                 float* __restrict__ dst2,
                                                 const float* __restrict__ thetas) {
    int b = blockIdx.y;
    int p4 = blockIdx.x * 256 + threadIdx.x;
    int p = p4 * 4;
    int y = p >> 9, x0p = p & 511;
    const float* th = thetas + b * 6;
    const float* im = src + (size_t)b * NPIX;
    float t0 = th[0], t1 = th[1], t2 = th[2], t3 = th[3], t4 = th[4], t5 = th[5];
    float Y = (2.0f * (float)y + 1.0f) / 512.0f - 1.0f;
    float r[4];
    #pragma unroll
    for (int k = 0; k < 4; ++k) {
        float X = (2.0f * (float)(x0p + k) + 1.0f) / 512.0f - 1.0f;
        float gx = t0 * X + t1 * Y + t2;
        float gy = t3 * X + t4 * Y + t5;
        r[k] = gs_bilinear(im, 512, 512, gx, gy);
    }
    float4 v4 = make_float4(r[0], r[1], r[2], r[3]);
    *(float4*)(dst + (size_t)b * NPIX + p) = v4;
    if (dst2) *(float4*)(dst2 + (size_t)b * NPIX + p) = v4;
}

__device__ __forceinline__ float rm2_val(const float* mk, const float* t2, int cx_, int ry_) {
    float X2 = (2.0f * (float)cx_ + 1.0f) / 512.0f - 1.0f;
    float Y2 = (2.0f * (float)ry_ + 1.0f) / 512.0f - 1.0f;
    float g2x = t2[0] * X2 + t2[1] * Y2 + t2[2];
    float g2y = t2[3] * X2 + t2[4] * Y2 + t2[5];
    return gs_bilinear(mk, 512, 512, g2x, g2y);
}

// queue consumer: rm = gs(gs(mask_j, g2), g1) >= 0.5 on live tiles (out3 pre-zeroed)
__global__ void __launch_bounds__(256) k_mask_live(const float* __restrict__ masks,
                                                   float* __restrict__ out3,
                                                   const float* __restrict__ inv1,
                                                   const float* __restrict__ inv2,
                                                   const int* __restrict__ queue,
                                                   const int* __restrict__ qcount,
                                                   int* __restrict__ bbox) {
    __shared__ int sbb[4];
    int n = *qcount;
    for (int q = blockIdx.x; q < n; q += gridDim.x) {
        int e = queue[q];
        int jb = e >> 10, tile = e & 1023;
        if (threadIdx.x == 0) { sbb[0] = INT_MAX; sbb[1] = INT_MAX; sbb[2] = INT_MIN; sbb[3] = INT_MIN; }
        __syncthreads();

        int ty = tile >> 5, tx = tile & 31;
        int y = ty * 16 + (threadIdx.x >> 4);
        int x = tx * 16 + (threadIdx.x & 15);
        int j = jb >> 4, b = jb & 15;
        const float* t1 = inv1 + b * 6;
        const float* t2 = inv2 + b * 6;
        const float* mk = masks + (size_t)j * NPIX;

        float X = (2.0f * (float)x + 1.0f) / 512.0f - 1.0f;
        float Y = (2.0f * (float)y + 1.0f) / 512.0f - 1.0f;
        float gx = t1[0] * X + t1[1] * Y + t1[2];
        float gy = t1[3] * X + t1[4] * Y + t1[5];
        float sx = ((gx + 1.0f) * 512.0f - 1.0f) * 0.5f;
        float sy = ((gy + 1.0f) * 512.0f - 1.0f) * 0.5f;
        float xf = floorf(sx), yf = floorf(sy);
        int ix = (int)xf, iy = (int)yf;
        float wx = sx - xf, wy = sy - yf;

        float v = 0.0f;
        bool vx0 = (ix >= 0) && (ix < 512);
        bool vx1 = (ix >= -1) && (ix < 511);
        bool vy0 = (iy >= 0) && (iy < 512);
        bool vy1 = (iy >= -1) && (iy < 511);
        if (vx0 && vy0) v += rm2_val(mk, t2, ix,     iy    ) * ((1.0f - wx) * (1.0f - wy));
        if (vx1 && vy0) v += rm2_val(mk, t2, ix + 1, iy    ) * (wx * (1.0f - wy));
        if (vx0 && vy1) v += rm2_val(mk, t2, ix,     iy + 1) * ((1.0f - wx) * wy);
        if (vx1 && vy1) v += rm2_val(mk, t2, ix + 1, iy + 1) * (wx * wy);

        float res = 0.0f;
        if (v >= 0.5f) {
            res = 1.0f;
            atomicMin(&sbb[0], y); atomicMin(&sbb[1], x);
            atomicMax(&sbb[2], y); atomicMax(&sbb[3], x);
        }
        out3[(size_t)jb * NPIX + y * 512 + x] = res;

        __syncthreads();
        if (threadIdx.x == 0 && sbb[2] != INT_MIN) {
            atomicMin(&bbox[jb * 4 + 0], sbb[0]);
            atomicMin(&bbox[jb * 4 + 1], sbb[1]);
            atomicMax(&bbox[jb * 4 + 2], sbb[2]);
            atomicMax(&bbox[jb * 4 + 3], sbb[3]);
        }
        __syncthreads();
    }
}

// fused COM stats: one block per (j,b); phase A -> threshold (LDS), phase B -> crop origin
__global__ void __launch_bounds__(256) k_stats(const float* __restrict__ pred,
                                               const float* __restrict__ mrot,
                                               const int* __restrict__ bbox,
                                               int* __restrict__ xy) {
    int jb = blockIdx.x;
    int b = jb & 15;
    int rmin = bbox[jb*4+0], cmin = bbox[jb*4+1], rmax = bbox[jb*4+2], cmax = bbox[jb*4+3];
    const float* img = pred + (size_t)b * NPIX;
    const float* mk  = mrot + (size_t)jb * NPIX;
    int lane = threadIdx.x & 63, w = threadIdx.x >> 6;
    int W = cmax - cmin + 1;
    int total = (rmax >= rmin) ? W * (rmax - rmin + 1) : 0;

    // phase A: sum(mask), sum(img*mask)
    double msum = 0.0, isum = 0.0;
    for (int i = threadIdx.x; i < total; i += 256) {
        int r = rmin + i / W, c = cmin + i % W;
        float m = mk[r * 512 + c];
        if (m != 0.0f) {
            msum += (double)m;
            isum += (double)(img[r * 512 + c] * m);
        }
    }
    for (int o = 32; o > 0; o >>= 1) {
        msum += __shfl_down(msum, o, 64);
        isum += __shfl_down(isum, o, 64);
    }
    __shared__ double s0[4], s1[4], s2[4];
    __shared__ double sthr;
    if (lane == 0) { s0[w] = msum; s1[w] = isum; }
    __syncthreads();
    if (threadIdx.x == 0) {
        double M = s0[0] + s0[1] + s0[2] + s0[3];
        double I = s1[0] + s1[1] + s1[2] + s1[3];
        sthr = (I / fmax(M, 1.0)) * 1.5;
    }
    __syncthreads();
    double t = sthr;

    // phase B: thresholded weighted centroid
    double wsum = 0.0, sy = 0.0, sx = 0.0;
    for (int i = threadIdx.x; i < total; i += 256) {
        int r = rmin + i / W, c = cmin + i % W;
        float m = mk[r * 512 + c];
        if (m != 0.0f) {
            float v = img[r * 512 + c] * m;
            if ((double)v > t) {
                double vd = (double)v;
                wsum += vd;
                sy += vd * (double)r;   // row (cx in reference)
                sx += vd * (double)c;   // col (cy in reference)
            }
        }
    }
    for (int o = 32; o > 0; o >>= 1) {
        wsum += __shfl_down(wsum, o, 64);
        sy   += __shfl_down(sy,   o, 64);
        sx   += __shfl_down(sx,   o, 64);
    }
    __syncthreads();
    if (lane == 0) { s0[w] = wsum; s1[w] = sy; s2[w] = sx; }
    __syncthreads();
    if (threadIdx.x == 0) {
        double W_ = s0[0] + s0[1] + s0[2] + s0[3];
        double SY = s1[0] + s1[1] + s1[2] + s1[3];
        double SX = s2[0] + s2[1] + s2[2] + s2[3];
        double tot = W_ + 1e-8;
        int x0 = (int)rint(SY / tot) - RAD;
        int y0 = (int)rint(SX / tot) - RAD;
        x0 = min(max(x0, 0), 512 - DSZ);
        y0 = min(max(y0, 0), 512 - DSZ);
        xy[jb * 2 + 0] = x0;
        xy[jb * 2 + 1] = y0;
    }
}

// one patch pass: crop->dot divide->grid_sample->write back (LDS stride PSTR)
__device__ __forceinline__ void patch_one(float* __restrict__ im, float* __restrict__ patch,
                                          int x0, int y0, float a,
                                          float t0, float t1, float t2,
                                          float t3, float t4, float t5) {
    for (int t = threadIdx.x; t < DSZ * DSZ; t += 1024) {
        int u = t / DSZ, v = t % DSZ;
        float val = im[(x0 + u) * 512 + (y0 + v)];
        int du = u - RAD, dv = v - RAD;
        if (du * du + dv * dv <= 16) val = val / a;
        patch[u * PSTR + v] = val;
    }
    __syncthreads();
    for (int t = threadIdx.x; t < DSZ * DSZ; t += 1024) {
        int py = t / DSZ, px = t % DSZ;
        float X = (2.0f * (float)px + 1.0f) / 120.0f - 1.0f;
        float Y = (2.0f * (float)py + 1.0f) / 120.0f - 1.0f;
        float gx = t0 * X + t1 * Y + t2;
        float gy = t3 * X + t4 * Y + t5;
        float o = gs_bilinear_patch(patch, gx, gy);
        im[(x0 + py) * 512 + (y0 + px)] = o;
    }
}

// revise: one block per (b,j). Disjoint rects (the common case) run all 4 j in
// parallel — provably independent, identical to sequential order. If any rects
// of the same b overlap, block j=0 runs all 4 sequentially; j>0 blocks exit.
__global__ void __launch_bounds__(1024) k_patch(float* __restrict__ img,
                                                const int* __restrict__ xy,
                                                const float* __restrict__ inv1,
                                                const float* __restrict__ adj) {
    __shared__ float patch[DSZ * PSTR];
    int b = blockIdx.x >> 2, j = blockIdx.x & 3;
    int rx[4], ry[4];
    #pragma unroll
    for (int k = 0; k < 4; ++k) {
        rx[k] = xy[(k * 16 + b) * 2 + 0];
        ry[k] = xy[(k * 16 + b) * 2 + 1];
    }
    bool overlap = false;
    #pragma unroll
    for (int i = 0; i < 4; ++i)
        #pragma unroll
        for (int k = 0; k < 4; ++k)
            if (i < k && abs(rx[i] - rx[k]) < DSZ && abs(ry[i] - ry[k]) < DSZ)
                overlap = true;

    float a = adj[b];
    float* im = img + (size_t)b * NPIX;
    const float* th = inv1 + b * 6;
    float t0 = th[0], t1 = th[1], t2 = th[2], t3 = th[3], t4 = th[4], t5 = th[5];

    if (!overlap) {
        patch_one(im, patch, rx[j], ry[j], a, t0, t1, t2, t3, t4, t5);
    } else {
        if (j != 0) return;
        for (int jj = 0; jj < 4; ++jj) {
            patch_one(im, patch, rx[jj], ry[jj], a, t0, t1, t2, t3, t4, t5);
            __threadfence_block();
            __syncthreads();
        }
    }
}

// ---------------- launcher ----------------

extern "C" void kernel_launch(void* const* d_in, const int* in_sizes, int n_in,
                              void* d_out, int out_size, void* d_ws, size_t ws_size,
                              hipStream_t stream) {
    const float* base  = (const float*)d_in[0];
    const float* sc    = (const float*)d_in[1];
    const float* rot   = (const float*)d_in[2];
    const float* tr    = (const float*)d_in[3];
    const float* adj   = (const float*)d_in[4];
    const float* masks = (const float*)d_in[5];

    float* out  = (float*)d_out;
    float* out0 = out;                               // base_inp
    float* out1 = out0 + (size_t)NB * NPIX;          // pred_input
    float* out2 = out1 + (size_t)NB * NPIX;          // pred_revise
    float* out3 = out2 + (size_t)NB * NPIX;          // masks_rot (4,16,512,512)

    // ws layout (bytes): inv @0, xy @4096, bbox @8192, occ @12288,
    //                    qcount @16128, queue @16384 (256 KB)
    float*    inv1   = (float*)d_ws;
    float*    inv2   = inv1 + 96;
    float*    inv3   = inv1 + 192;
    int*      xy     = (int*)((char*)d_ws + 4096);
    int*      bbox   = (int*)((char*)d_ws + 8192);
    unsigned* occ    = (unsigned*)((char*)d_ws + 12288);
    int*      qcount = (int*)((char*)d_ws + 16128);
    int*      queue  = (int*)((char*)d_ws + 16384);

    dim3 gridImg4(256, NB);   // 4 px/thread kernels

    k_prep<<<1, 256, 0, stream>>>(sc, rot, tr, (float*)d_ws, bbox, occ, qcount);
    k_occ<<<1024, 256, 0, stream>>>(masks, occ);
    k_otile<<<256, 256, 0, stream>>>(occ, inv1, inv2, queue, qcount);
    k_upsample<<<gridImg4, 256, 0, stream>>>(base, out0);

    // image chain: base_inp -g3-> tmpA(out2) -g2-> tmpB(out3[:16]) -g1-> out1 (+out2 copy)
    k_gsample<<<gridImg4, 256, 0, stream>>>(out0, out2, nullptr, inv3);
    k_gsample<<<gridImg4, 256, 0, stream>>>(out2, out3, nullptr, inv2);
    k_gsample<<<gridImg4, 256, 0, stream>>>(out3, out1, out2, inv1);  // dual store

    // masks: zero-fill (coalesced) then compute live tiles from the queue
    k_zero<<<2048, 256, 0, stream>>>((float4*)out3, 64 * NPIX / 4);
    k_mask_live<<<1024, 256, 0, stream>>>(masks, out3, inv1, inv2, queue, qcount, bbox);

    // fused COM stats over per-(j,b) bounding boxes
    k_stats<<<64, 256, 0, stream>>>(out1, out3, bbox, xy);

    // revise: 64 blocks, parallel when rects disjoint (deterministic fallback if not)
    k_patch<<<64, 1024, 0, stream>>>(out2, xy, inv1, adj);
}

// Round 8
// 246.971 us; speedup vs baseline: 1.6752x; 1.1276x over previous
//
#include <hip/hip_runtime.h>
#include <math.h>
#include <limits.h>

#define NPIX (512*512)
#define NB 16
#define RAD 60
#define DSZ 120
#define PSTR 121   // padded LDS stride for patch kernel
#define GTS 48     // gsample LDS rect size
#define GSTR 49    // gsample LDS row stride (conflict break)

// ---------------- device helpers ----------------

// torch/jax grid_sample semantics: bilinear, zero padding, align_corners=False
__device__ __forceinline__ float gs_bilinear(const float* img, int H, int W,
                                             float gx, float gy) {
    float x = ((gx + 1.0f) * (float)W - 1.0f) * 0.5f;
    float y = ((gy + 1.0f) * (float)H - 1.0f) * 0.5f;
    float xf = floorf(x), yf = floorf(y);
    int ix = (int)xf, iy = (int)yf;
    float wx = x - xf, wy = y - yf;
    float v = 0.0f;
    bool vx0 = (ix >= 0) && (ix < W);
    bool vx1 = (ix >= -1) && (ix < W - 1);
    bool vy0 = (iy >= 0) && (iy < H);
    bool vy1 = (iy >= -1) && (iy < H - 1);
    if (vx0 && vy0) v += img[iy*W + ix]         * ((1.0f - wx) * (1.0f - wy));
    if (vx1 && vy0) v += img[iy*W + ix + 1]     * (wx * (1.0f - wy));
    if (vx0 && vy1) v += img[(iy+1)*W + ix]     * ((1.0f - wx) * wy);
    if (vx1 && vy1) v += img[(iy+1)*W + ix + 1] * (wx * wy);
    return v;
}

// same semantics but LDS patch with padded row stride PSTR, logical 120x120
__device__ __forceinline__ float gs_bilinear_patch(const float* img, float gx, float gy) {
    float x = ((gx + 1.0f) * 120.0f - 1.0f) * 0.5f;
    float y = ((gy + 1.0f) * 120.0f - 1.0f) * 0.5f;
    float xf = floorf(x), yf = floorf(y);
    int ix = (int)xf, iy = (int)yf;
    float wx = x - xf, wy = y - yf;
    float v = 0.0f;
    bool vx0 = (ix >= 0) && (ix < 120);
    bool vx1 = (ix >= -1) && (ix < 119);
    bool vy0 = (iy >= 0) && (iy < 120);
    bool vy1 = (iy >= -1) && (iy < 119);
    if (vx0 && vy0) v += img[iy*PSTR + ix]         * ((1.0f - wx) * (1.0f - wy));
    if (vx1 && vy0) v += img[iy*PSTR + ix + 1]     * (wx * (1.0f - wy));
    if (vx0 && vy1) v += img[(iy+1)*PSTR + ix]     * ((1.0f - wx) * wy);
    if (vx1 && vy1) v += img[(iy+1)*PSTR + ix + 1] * (wx * wy);
    return v;
}

// ---------------- kernels ----------------

// inverses + per-call ws init (bbox sentinels, occ zeros, queue counter)
__global__ void k_prep(const float* __restrict__ sc, const float* __restrict__ rot,
                       const float* __restrict__ tr, float* __restrict__ ws_inv,
                       int* __restrict__ bbox, unsigned* __restrict__ occ,
                       int* __restrict__ qcount) {
    int t = threadIdx.x;
    if (t < 48) {
        int m = t >> 4, b = t & 15;
        const float* th = (m == 0 ? sc : (m == 1 ? rot : tr)) + b * 6;
        float a  = th[0], bb = th[1], tx = th[2];
        float c  = th[3], d  = th[4], ty = th[5];
        float L10 = c / a;
        float dp  = d  - L10 * bb;
        float typ = ty - L10 * tx;
        float i10 = (0.0f - L10) / dp;
        float i00 = (1.0f - bb * i10) / a;
        float i11 = 1.0f / dp;
        float i01 = (0.0f - bb * i11) / a;
        float i12 = (0.0f - typ) / dp;
        float i02 = (0.0f - bb * i12 - tx) / a;
        float* o = ws_inv + m * 96 + b * 6;
        o[0] = i00; o[1] = i01; o[2] = i02;
        o[3] = i10; o[4] = i11; o[5] = i12;
    }
    // bbox[jb*4 + {0:rmin,1:cmin,2:rmax,3:cmax}]
    bbox[t] = ((t & 3) < 2) ? INT_MAX : INT_MIN;
    if (t < 128) occ[t] = 0u;
    if (t == 0) *qcount = 0;
}

// mask-space occupancy: 1 bit per 16x16 tile per mask. 4 tiles/block (1 wave each).
__global__ void __launch_bounds__(256) k_occ(const float* __restrict__ masks,
                                             unsigned* __restrict__ occ) {
    int tile = blockIdx.x * 4 + (threadIdx.x >> 6);  // 0..4095
    int lane = threadIdx.x & 63;
    int j = tile >> 10, t = tile & 1023;
    int ty = t >> 5, tx = t & 31;
    const float* mk = masks + (size_t)j * NPIX;
    int any = 0;
    for (int i = lane; i < 256; i += 64) {
        int py = ty * 16 + (i >> 4), px = tx * 16 + (i & 15);
        if (mk[py * 512 + px] != 0.0f) any = 1;
    }
    unsigned long long m = __ballot(any);
    if (lane == 0 && m) atomicOr(&occ[j * 32 + ty], 1u << tx);
}

// classify each (jb, output 16x16 tile); live tiles -> work queue.
__global__ void __launch_bounds__(256) k_otile(const unsigned* __restrict__ occ,
                                               const float* __restrict__ inv1,
                                               const float* __restrict__ inv2,
                                               int* __restrict__ queue,
                                               int* __restrict__ qcount) {
    int idx = blockIdx.x * 256 + threadIdx.x;   // 0..65535
    int jb = idx >> 10, tile = idx & 1023;
    int j = jb >> 4, b = jb & 15;
    int ty = tile >> 5, tx = tile & 31;
    const float* t1 = inv1 + b * 6;
    const float* t2 = inv2 + b * 6;
    float xs[2] = { (float)(tx * 16), (float)(tx * 16 + 15) };
    float ys[2] = { (float)(ty * 16), (float)(ty * 16 + 15) };
    float sxmin = 1e30f, sxmax = -1e30f, symin = 1e30f, symax = -1e30f;
    for (int cy = 0; cy < 2; ++cy)
        for (int cx = 0; cx < 2; ++cx) {
            float X = (2.0f * xs[cx] + 1.0f) / 512.0f - 1.0f;
            float Y = (2.0f * ys[cy] + 1.0f) / 512.0f - 1.0f;
            float gx = t1[0] * X + t1[1] * Y + t1[2];
            float gy = t1[3] * X + t1[4] * Y + t1[5];
            float sx = ((gx + 1.0f) * 512.0f - 1.0f) * 0.5f;
            float sy = ((gy + 1.0f) * 512.0f - 1.0f) * 0.5f;
            sxmin = fminf(sxmin, sx); sxmax = fmaxf(sxmax, sx);
            symin = fminf(symin, sy); symax = fmaxf(symax, sy);
        }
    int c0 = max((int)floorf(sxmin) - 1, 0), c1 = min((int)floorf(sxmax) + 2, 511);
    int r0 = max((int)floorf(symin) - 1, 0), r1 = min((int)floorf(symax) + 2, 511);
    bool any = false;
    if (c0 <= c1 && r0 <= r1) {
        float A0 = t2[0], A1 = t2[1], A3 = t2[3], A4 = t2[4];
        float Kx = 0.5f * (-511.0f * (A0 + A1) + 512.0f * t2[2] + 511.0f);
        float Ky = 0.5f * (-511.0f * (A3 + A4) + 512.0f * t2[5] + 511.0f);
        float pxmin = A0 * (A0 >= 0.f ? c0 : c1) + A1 * (A1 >= 0.f ? r0 : r1) + Kx;
        float pxmax = A0 * (A0 >= 0.f ? c1 : c0) + A1 * (A1 >= 0.f ? r1 : r0) + Kx;
        float pymin = A3 * (A3 >= 0.f ? c0 : c1) + A4 * (A4 >= 0.f ? r0 : r1) + Ky;
        float pymax = A3 * (A3 >= 0.f ? c1 : c0) + A4 * (A4 >= 0.f ? r1 : r0) + Ky;
        int xlo = max((int)floorf(pxmin) - 1, 0), xhi = min((int)floorf(pxmax) + 2, 511);
        int ylo = max((int)floorf(pymin) - 1, 0), yhi = min((int)floorf(pymax) + 2, 511);
        if (xlo <= xhi && ylo <= yhi)
            for (int tr = ylo >> 4; tr <= yhi >> 4; ++tr)
                for (int tc = xlo >> 4; tc <= xhi >> 4; ++tc)
                    if ((occ[j * 32 + tr] >> tc) & 1u) any = true;
    }
    if (any) {
        int pos = atomicAdd(qcount, 1);
        queue[pos] = (jb << 10) | tile;   // disjoint writes; order irrelevant
    }
}

// coalesced float4 zero-fill (out3 region)
__global__ void __launch_bounds__(256) k_zero(float4* __restrict__ p, int n4) {
    int stride = gridDim.x * 256;
    for (int i = blockIdx.x * 256 + threadIdx.x; i < n4; i += stride)
        p[i] = make_float4(0.f, 0.f, 0.f, 0.f);
}

// jax.image.resize linear 128->512; 4 px per thread, float4 store
__global__ void __launch_bounds__(256) k_upsample(const float* __restrict__ in,
                                                  float* __restrict__ out) {
    int b = blockIdx.y;
    int p4 = blockIdx.x * 256 + threadIdx.x;      // 0..65535
    int p = p4 * 4;
    int y = p >> 9, x0p = p & 511;
    const float* src = in + b * 128 * 128;
    float r[4];
    float sy = (float)y * 0.25f - 0.375f;
    float fy0 = floorf(sy);
    int iy = (int)fy0;
    float fy = sy - fy0;
    int iy0 = min(max(iy, 0), 127), iy1 = min(max(iy + 1, 0), 127);
    #pragma unroll
    for (int k = 0; k < 4; ++k) {
        int x = x0p + k;
        float sx = (float)x * 0.25f - 0.375f;
        float fx0 = floorf(sx);
        int ix = (int)fx0;
        float fx = sx - fx0;
        int ix0 = min(max(ix, 0), 127), ix1 = min(max(ix + 1, 0), 127);
        float v00 = src[iy0 * 128 + ix0], v10 = src[iy0 * 128 + ix1];
        float v01 = src[iy1 * 128 + ix0], v11 = src[iy1 * 128 + ix1];
        r[k] = (v00 * (1.0f - fx) + v10 * fx) * (1.0f - fy)
             + (v01 * (1.0f - fx) + v11 * fx) * fy;
    }
    *(float4*)(out + (size_t)b * NPIX + p) = make_float4(r[0], r[1], r[2], r[3]);
}

// LDS-tiled affine grid_sample: one 32x32 output tile per block, source rect
// staged in LDS (zero outside image == reference's zero-weight OOB taps).
// Per-pixel sample math identical to the direct path -> bitwise-identical output.
__global__ void __launch_bounds__(256) k_gsample(const float* __restrict__ src,
                                                 float* __restrict__ dst,
                                                 float* __restrict__ dst2,
                                                 const float* __restrict__ thetas) {
    __shared__ float tb[GTS * GSTR];
    int b = blockIdx.y;
    int tile = blockIdx.x;             // 0..255
    int ox = (tile & 15) * 32, oy = (tile >> 4) * 32;
    const float* th = thetas + b * 6;
    float t0 = th[0], t1 = th[1], t2 = th[2], t3 = th[3], t4 = th[4], t5 = th[5];
    const float* im = src + (size_t)b * NPIX;

    // corner-exact source-space bbox of this output tile (+1 texel rounding pad)
    float sxmin = 1e30f, sxmax = -1e30f, symin = 1e30f, symax = -1e30f;
    #pragma unroll
    for (int cy = 0; cy < 2; ++cy)
        #pragma unroll
        for (int cx = 0; cx < 2; ++cx) {
            float X = (2.0f * (float)(ox + cx * 31) + 1.0f) / 512.0f - 1.0f;
            float Y = (2.0f * (float)(oy + cy * 31) + 1.0f) / 512.0f - 1.0f;
            float gx = t0 * X + t1 * Y + t2;
            float gy = t3 * X + t4 * Y + t5;
            float sx = ((gx + 1.0f) * 512.0f - 1.0f) * 0.5f;
            float sy = ((gy + 1.0f) * 512.0f - 1.0f) * 0.5f;
            sxmin = fminf(sxmin, sx); sxmax = fmaxf(sxmax, sx);
            symin = fminf(symin, sy); symax = fmaxf(symax, sy);
        }
    int rx0 = (int)floorf(sxmin) - 1;
    int ry0 = (int)floorf(symin) - 1;
    bool fits = ((int)floorf(sxmax) + 2 - rx0 < GTS) &&
                ((int)floorf(symax) + 2 - ry0 < GTS);

    int t = threadIdx.x;
    int py = oy + (t >> 3);
    int px0 = ox + (t & 7) * 4;
    float Y = (2.0f * (float)py + 1.0f) / 512.0f - 1.0f;
    float r[4];

    if (fits) {
        for (int i = t; i < GTS * GTS; i += 256) {
            int rr = i / GTS, cc = i - rr * GTS;
            int gy_ = ry0 + rr, gx_ = rx0 + cc;
            float v = 0.0f;
            if (gx_ >= 0 && gx_ < 512 && gy_ >= 0 && gy_ < 512)
                v = im[gy_ * 512 + gx_];
            tb[rr * GSTR + cc] = v;
        }
        __syncthreads();
        #pragma unroll
        for (int k = 0; k < 4; ++k) {
            float X = (2.0f * (float)(px0 + k) + 1.0f) / 512.0f - 1.0f;
            float gx = t0 * X + t1 * Y + t2;
            float gy = t3 * X + t4 * Y + t5;
            float x = ((gx + 1.0f) * 512.0f - 1.0f) * 0.5f;
            float y = ((gy + 1.0f) * 512.0f - 1.0f) * 0.5f;
            float xf = floorf(x), yf = floorf(y);
            int ix = (int)xf, iy = (int)yf;
            float wx = x - xf, wy = y - yf;
            int lx = ix - rx0, ly = iy - ry0;   // provably in [0,GTS-1)
            float v;
            v  = tb[ly * GSTR + lx]           * ((1.0f - wx) * (1.0f - wy));
            v += tb[ly * GSTR + lx + 1]       * (wx * (1.0f - wy));
            v += tb[(ly + 1) * GSTR + lx]     * ((1.0f - wx) * wy);
            v += tb[(ly + 1) * GSTR + lx + 1] * (wx * wy);
            r[k] = v;
        }
    } else {
        #pragma unroll
        for (int k = 0; k < 4; ++k) {
            float X = (2.0f * (float)(px0 + k) + 1.0f) / 512.0f - 1.0f;
            float gx = t0 * X + t1 * Y + t2;
            float gy = t3 * X + t4 * Y + t5;
            r[k] = gs_bilinear(im, 512, 512, gx, gy);
        }
    }
    float4 v4 = make_float4(r[0], r[1], r[2], r[3]);
    size_t op = (size_t)b * NPIX + py * 512 + px0;
    *(float4*)(dst + op) = v4;
    if (dst2) *(float4*)(dst2 + op) = v4;
}

__device__ __forceinline__ float rm2_val(const float* mk, const float* t2, int cx_, int ry_) {
    float X2 = (2.0f * (float)cx_ + 1.0f) / 512.0f - 1.0f;
    float Y2 = (2.0f * (float)ry_ + 1.0f) / 512.0f - 1.0f;
    float g2x = t2[0] * X2 + t2[1] * Y2 + t2[2];
    float g2y = t2[3] * X2 + t2[4] * Y2 + t2[5];
    return gs_bilinear(mk, 512, 512, g2x, g2y);
}

// queue consumer: rm = gs(gs(mask_j, g2), g1) >= 0.5 on live tiles (out3 pre-zeroed)
__global__ void __launch_bounds__(256) k_mask_live(const float* __restrict__ masks,
                                                   float* __restrict__ out3,
                                                   const float* __restrict__ inv1,
                                                   const float* __restrict__ inv2,
                                                   const int* __restrict__ queue,
                                                   const int* __restrict__ qcount,
                                                   int* __restrict__ bbox) {
    __shared__ int sbb[4];
    int n = *qcount;
    for (int q = blockIdx.x; q < n; q += gridDim.x) {
        int e = queue[q];
        int jb = e >> 10, tile = e & 1023;
        if (threadIdx.x == 0) { sbb[0] = INT_MAX; sbb[1] = INT_MAX; sbb[2] = INT_MIN; sbb[3] = INT_MIN; }
        __syncthreads();

        int ty = tile >> 5, tx = tile & 31;
        int y = ty * 16 + (threadIdx.x >> 4);
        int x = tx * 16 + (threadIdx.x & 15);
        int j = jb >> 4, b = jb & 15;
        const float* t1 = inv1 + b * 6;
        const float* t2 = inv2 + b * 6;
        const float* mk = masks + (size_t)j * NPIX;

        float X = (2.0f * (float)x + 1.0f) / 512.0f - 1.0f;
        float Y = (2.0f * (float)y + 1.0f) / 512.0f - 1.0f;
        float gx = t1[0] * X + t1[1] * Y + t1[2];
        float gy = t1[3] * X + t1[4] * Y + t1[5];
        float sx = ((gx + 1.0f) * 512.0f - 1.0f) * 0.5f;
        float sy = ((gy + 1.0f) * 512.0f - 1.0f) * 0.5f;
        float xf = floorf(sx), yf = floorf(sy);
        int ix = (int)xf, iy = (int)yf;
        float wx = sx - xf, wy = sy - yf;

        float v = 0.0f;
        bool vx0 = (ix >= 0) && (ix < 512);
        bool vx1 = (ix >= -1) && (ix < 511);
        bool vy0 = (iy >= 0) && (iy < 512);
        bool vy1 = (iy >= -1) && (iy < 511);
        if (vx0 && vy0) v += rm2_val(mk, t2, ix,     iy    ) * ((1.0f - wx) * (1.0f - wy));
        if (vx1 && vy0) v += rm2_val(mk, t2, ix + 1, iy    ) * (wx * (1.0f - wy));
        if (vx0 && vy1) v += rm2_val(mk, t2, ix,     iy + 1) * ((1.0f - wx) * wy);
        if (vx1 && vy1) v += rm2_val(mk, t2, ix + 1, iy + 1) * (wx * wy);

        float res = 0.0f;
        if (v >= 0.5f) {
            res = 1.0f;
            atomicMin(&sbb[0], y); atomicMin(&sbb[1], x);
            atomicMax(&sbb[2], y); atomicMax(&sbb[3], x);
        }
        out3[(size_t)jb * NPIX + y * 512 + x] = res;

        __syncthreads();
        if (threadIdx.x == 0 && sbb[2] != INT_MIN) {
            atomicMin(&bbox[jb * 4 + 0], sbb[0]);
            atomicMin(&bbox[jb * 4 + 1], sbb[1]);
            atomicMax(&bbox[jb * 4 + 2], sbb[2]);
            atomicMax(&bbox[jb * 4 + 3], sbb[3]);
        }
        __syncthreads();
    }
}

// fused COM stats: one block per (j,b); phase A -> threshold (LDS), phase B -> crop origin
__global__ void __launch_bounds__(256) k_stats(const float* __restrict__ pred,
                                               const float* __restrict__ mrot,
                                               const int* __restrict__ bbox,
                                               int* __restrict__ xy) {
    int jb = blockIdx.x;
    int b = jb & 15;
    int rmin = bbox[jb*4+0], cmin = bbox[jb*4+1], rmax = bbox[jb*4+2], cmax = bbox[jb*4+3];
    const float* img = pred + (size_t)b * NPIX;
    const float* mk  = mrot + (size_t)jb * NPIX;
    int lane = threadIdx.x & 63, w = threadIdx.x >> 6;
    int W = cmax - cmin + 1;
    int total = (rmax >= rmin) ? W * (rmax - rmin + 1) : 0;

    // phase A: sum(mask), sum(img*mask)
    double msum = 0.0, isum = 0.0;
    for (int i = threadIdx.x; i < total; i += 256) {
        int r = rmin + i / W, c = cmin + i % W;
        float m = mk[r * 512 + c];
        if (m != 0.0f) {
            msum += (double)m;
            isum += (double)(img[r * 512 + c] * m);
        }
    }
    for (int o = 32; o > 0; o >>= 1) {
        msum += __shfl_down(msum, o, 64);
        isum += __shfl_down(isum, o, 64);
    }
    __shared__ double s0[4], s1[4], s2[4];
    __shared__ double sthr;
    if (lane == 0) { s0[w] = msum; s1[w] = isum; }
    __syncthreads();
    if (threadIdx.x == 0) {
        double M = s0[0] + s0[1] + s0[2] + s0[3];
        double I = s1[0] + s1[1] + s1[2] + s1[3];
        sthr = (I / fmax(M, 1.0)) * 1.5;
    }
    __syncthreads();
    double t = sthr;

    // phase B: thresholded weighted centroid
    double wsum = 0.0, sy = 0.0, sx = 0.0;
    for (int i = threadIdx.x; i < total; i += 256) {
        int r = rmin + i / W, c = cmin + i % W;
        float m = mk[r * 512 + c];
        if (m != 0.0f) {
            float v = img[r * 512 + c] * m;
            if ((double)v > t) {
                double vd = (double)v;
                wsum += vd;
                sy += vd * (double)r;   // row (cx in reference)
                sx += vd * (double)c;   // col (cy in reference)
            }
        }
    }
    for (int o = 32; o > 0; o >>= 1) {
        wsum += __shfl_down(wsum, o, 64);
        sy   += __shfl_down(sy,   o, 64);
        sx   += __shfl_down(sx,   o, 64);
    }
    __syncthreads();
    if (lane == 0) { s0[w] = wsum; s1[w] = sy; s2[w] = sx; }
    __syncthreads();
    if (threadIdx.x == 0) {
        double W_ = s0[0] + s0[1] + s0[2] + s0[3];
        double SY = s1[0] + s1[1] + s1[2] + s1[3];
        double SX = s2[0] + s2[1] + s2[2] + s2[3];
        double tot = W_ + 1e-8;
        int x0 = (int)rint(SY / tot) - RAD;
        int y0 = (int)rint(SX / tot) - RAD;
        x0 = min(max(x0, 0), 512 - DSZ);
        y0 = min(max(y0, 0), 512 - DSZ);
        xy[jb * 2 + 0] = x0;
        xy[jb * 2 + 1] = y0;
    }
}

// one patch pass: crop->dot divide->grid_sample->write back (LDS stride PSTR)
__device__ __forceinline__ void patch_one(float* __restrict__ im, float* __restrict__ patch,
                                          int x0, int y0, float a,
                                          float t0, float t1, float t2,
                                          float t3, float t4, float t5) {
    for (int t = threadIdx.x; t < DSZ * DSZ; t += 1024) {
        int u = t / DSZ, v = t % DSZ;
        float val = im[(x0 + u) * 512 + (y0 + v)];
        int du = u - RAD, dv = v - RAD;
        if (du * du + dv * dv <= 16) val = val / a;
        patch[u * PSTR + v] = val;
    }
    __syncthreads();
    for (int t = threadIdx.x; t < DSZ * DSZ; t += 1024) {
        int py = t / DSZ, px = t % DSZ;
        float X = (2.0f * (float)px + 1.0f) / 120.0f - 1.0f;
        float Y = (2.0f * (float)py + 1.0f) / 120.0f - 1.0f;
        float gx = t0 * X + t1 * Y + t2;
        float gy = t3 * X + t4 * Y + t5;
        float o = gs_bilinear_patch(patch, gx, gy);
        im[(x0 + py) * 512 + (y0 + px)] = o;
    }
}

// revise: one block per (b,j). Disjoint rects run all 4 j in parallel (provably
// independent). If any same-b rects overlap, block j=0 runs all 4 sequentially.
__global__ void __launch_bounds__(1024) k_patch(float* __restrict__ img,
                                                const int* __restrict__ xy,
                                                const float* __restrict__ inv1,
                                                const float* __restrict__ adj) {
    __shared__ float patch[DSZ * PSTR];
    int b = blockIdx.x >> 2, j = blockIdx.x & 3;
    int rx[4], ry[4];
    #pragma unroll
    for (int k = 0; k < 4; ++k) {
        rx[k] = xy[(k * 16 + b) * 2 + 0];
        ry[k] = xy[(k * 16 + b) * 2 + 1];
    }
    bool overlap = false;
    #pragma unroll
    for (int i = 0; i < 4; ++i)
        #pragma unroll
        for (int k = 0; k < 4; ++k)
            if (i < k && abs(rx[i] - rx[k]) < DSZ && abs(ry[i] - ry[k]) < DSZ)
                overlap = true;

    float a = adj[b];
    float* im = img + (size_t)b * NPIX;
    const float* th = inv1 + b * 6;
    float t0 = th[0], t1 = th[1], t2 = th[2], t3 = th[3], t4 = th[4], t5 = th[5];

    if (!overlap) {
        patch_one(im, patch, rx[j], ry[j], a, t0, t1, t2, t3, t4, t5);
    } else {
        if (j != 0) return;
        for (int jj = 0; jj < 4; ++jj) {
            patch_one(im, patch, rx[jj], ry[jj], a, t0, t1, t2, t3, t4, t5);
            __threadfence_block();
            __syncthreads();
        }
    }
}

// ---------------- launcher ----------------

extern "C" void kernel_launch(void* const* d_in, const int* in_sizes, int n_in,
                              void* d_out, int out_size, void* d_ws, size_t ws_size,
                              hipStream_t stream) {
    const float* base  = (const float*)d_in[0];
    const float* sc    = (const float*)d_in[1];
    const float* rot   = (const float*)d_in[2];
    const float* tr    = (const float*)d_in[3];
    const float* adj   = (const float*)d_in[4];
    const float* masks = (const float*)d_in[5];

    float* out  = (float*)d_out;
    float* out0 = out;                               // base_inp
    float* out1 = out0 + (size_t)NB * NPIX;          // pred_input
    float* out2 = out1 + (size_t)NB * NPIX;          // pred_revise
    float* out3 = out2 + (size_t)NB * NPIX;          // masks_rot (4,16,512,512)

    // ws layout (bytes): inv @0, xy @4096, bbox @8192, occ @12288,
    //                    qcount @16128, queue @16384 (256 KB)
    float*    inv1   = (float*)d_ws;
    float*    inv2   = inv1 + 96;
    float*    inv3   = inv1 + 192;
    int*      xy     = (int*)((char*)d_ws + 4096);
    int*      bbox   = (int*)((char*)d_ws + 8192);
    unsigned* occ    = (unsigned*)((char*)d_ws + 12288);
    int*      qcount = (int*)((char*)d_ws + 16128);
    int*      queue  = (int*)((char*)d_ws + 16384);

    dim3 gridUp(256, NB);     // upsample: 4 px/thread linear
    dim3 gridTile(256, NB);   // gsample: 32x32 tile per block

    k_prep<<<1, 256, 0, stream>>>(sc, rot, tr, (float*)d_ws, bbox, occ, qcount);
    k_occ<<<1024, 256, 0, stream>>>(masks, occ);
    k_otile<<<256, 256, 0, stream>>>(occ, inv1, inv2, queue, qcount);
    k_upsample<<<gridUp, 256, 0, stream>>>(base, out0);

    // image chain: base_inp -g3-> tmpA(out2) -g2-> tmpB(out3[:16]) -g1-> out1 (+out2 copy)
    k_gsample<<<gridTile, 256, 0, stream>>>(out0, out2, nullptr, inv3);
    k_gsample<<<gridTile, 256, 0, stream>>>(out2, out3, nullptr, inv2);
    k_gsample<<<gridTile, 256, 0, stream>>>(out3, out1, out2, inv1);  // dual store

    // masks: zero-fill (coalesced) then compute live tiles from the queue
    k_zero<<<2048, 256, 0, stream>>>((float4*)out3, 64 * NPIX / 4);
    k_mask_live<<<1024, 256, 0, stream>>>(masks, out3, inv1, inv2, queue, qcount, bbox);

    // fused COM stats over per-(j,b) bounding boxes
    k_stats<<<64, 256, 0, stream>>>(out1, out3, bbox, xy);

    // revise: 64 blocks, parallel when rects disjoint (deterministic fallback if not)
    k_patch<<<64, 1024, 0, stream>>>(out2, xy, inv1, adj);
}

// Round 9
// 246.563 us; speedup vs baseline: 1.6780x; 1.0017x over previous
//
#include <hip/hip_runtime.h>
#include <math.h>
#include <limits.h>

#define NPIX (512*512)
#define NB 16
#define RAD 60
#define DSZ 120
#define PSTR 121   // padded LDS stride for patch kernel
#define GTS 48     // gsample LDS rect size
#define GSTR 49    // gsample LDS row stride (conflict break)

// ---------------- device helpers ----------------

// torch/jax grid_sample semantics: bilinear, zero padding, align_corners=False
__device__ __forceinline__ float gs_bilinear(const float* img, int H, int W,
                                             float gx, float gy) {
    float x = ((gx + 1.0f) * (float)W - 1.0f) * 0.5f;
    float y = ((gy + 1.0f) * (float)H - 1.0f) * 0.5f;
    float xf = floorf(x), yf = floorf(y);
    int ix = (int)xf, iy = (int)yf;
    float wx = x - xf, wy = y - yf;
    float v = 0.0f;
    bool vx0 = (ix >= 0) && (ix < W);
    bool vx1 = (ix >= -1) && (ix < W - 1);
    bool vy0 = (iy >= 0) && (iy < H);
    bool vy1 = (iy >= -1) && (iy < H - 1);
    if (vx0 && vy0) v += img[iy*W + ix]         * ((1.0f - wx) * (1.0f - wy));
    if (vx1 && vy0) v += img[iy*W + ix + 1]     * (wx * (1.0f - wy));
    if (vx0 && vy1) v += img[(iy+1)*W + ix]     * ((1.0f - wx) * wy);
    if (vx1 && vy1) v += img[(iy+1)*W + ix + 1] * (wx * wy);
    return v;
}

// LDS patch with padded row stride PSTR, logical 120x120
__device__ __forceinline__ float gs_bilinear_patch(const float* img, float gx, float gy) {
    float x = ((gx + 1.0f) * 120.0f - 1.0f) * 0.5f;
    float y = ((gy + 1.0f) * 120.0f - 1.0f) * 0.5f;
    float xf = floorf(x), yf = floorf(y);
    int ix = (int)xf, iy = (int)yf;
    float wx = x - xf, wy = y - yf;
    float v = 0.0f;
    bool vx0 = (ix >= 0) && (ix < 120);
    bool vx1 = (ix >= -1) && (ix < 119);
    bool vy0 = (iy >= 0) && (iy < 120);
    bool vy1 = (iy >= -1) && (iy < 119);
    if (vx0 && vy0) v += img[iy*PSTR + ix]         * ((1.0f - wx) * (1.0f - wy));
    if (vx1 && vy0) v += img[iy*PSTR + ix + 1]     * (wx * (1.0f - wy));
    if (vx0 && vy1) v += img[(iy+1)*PSTR + ix]     * ((1.0f - wx) * wy);
    if (vx1 && vy1) v += img[(iy+1)*PSTR + ix + 1] * (wx * wy);
    return v;
}

// ---------------- fused stage 1: prep + occ + upsample ----------------
// blocks [0,4096): upsample; [4096,4128): occ; 4128: prep
__global__ void __launch_bounds__(256) k_init(const float* __restrict__ base,
                                              const float* __restrict__ sc,
                                              const float* __restrict__ rot,
                                              const float* __restrict__ tr,
                                              const float* __restrict__ masks,
                                              float* __restrict__ out0,
                                              float* __restrict__ ws_inv,
                                              int* __restrict__ bbox,
                                              unsigned* __restrict__ occ,
                                              int* __restrict__ qcount) {
    int bid = blockIdx.x;
    if (bid < 4096) {
        // ---- upsample: jax.image.resize linear 128->512, 4 px/thread ----
        int b = bid >> 8;
        int p4 = (bid & 255) * 256 + threadIdx.x;
        int p = p4 * 4;
        int y = p >> 9, x0p = p & 511;
        const float* src = base + b * 128 * 128;
        float r[4];
        float sy = (float)y * 0.25f - 0.375f;
        float fy0 = floorf(sy);
        int iy = (int)fy0;
        float fy = sy - fy0;
        int iy0 = min(max(iy, 0), 127), iy1 = min(max(iy + 1, 0), 127);
        #pragma unroll
        for (int k = 0; k < 4; ++k) {
            int x = x0p + k;
            float sx = (float)x * 0.25f - 0.375f;
            float fx0 = floorf(sx);
            int ix = (int)fx0;
            float fx = sx - fx0;
            int ix0 = min(max(ix, 0), 127), ix1 = min(max(ix + 1, 0), 127);
            float v00 = src[iy0 * 128 + ix0], v10 = src[iy0 * 128 + ix1];
            float v01 = src[iy1 * 128 + ix0], v11 = src[iy1 * 128 + ix1];
            r[k] = (v00 * (1.0f - fx) + v10 * fx) * (1.0f - fy)
                 + (v01 * (1.0f - fx) + v11 * fx) * fy;
        }
        *(float4*)(out0 + (size_t)b * NPIX + p) = make_float4(r[0], r[1], r[2], r[3]);
    } else if (bid < 4128) {
        // ---- occ: one wave computes one occ word (tile-row of one mask) ----
        int word = (bid - 4096) * 4 + (threadIdx.x >> 6);   // 0..127
        int lane = threadIdx.x & 63;
        int j = word >> 5, ty = word & 31;
        const float* mk = masks + (size_t)j * NPIX + ty * 16 * 512 + lane * 8;
        int any = 0;
        for (int rr = 0; rr < 16; ++rr) {
            const float4* p = (const float4*)(mk + rr * 512);
            float4 a = p[0], c = p[1];
            if (a.x != 0.f || a.y != 0.f || a.z != 0.f || a.w != 0.f ||
                c.x != 0.f || c.y != 0.f || c.z != 0.f || c.w != 0.f) any = 1;
        }
        unsigned long long bb = __ballot(any);   // 2 lanes per 16-px tile
        if (lane == 0) {
            unsigned wrd = 0;
            for (int tx = 0; tx < 32; ++tx)
                if (bb & (3ull << (2 * tx))) wrd |= 1u << tx;
            occ[j * 32 + ty] = wrd;   // plain store: no init, no atomic
        }
    } else {
        // ---- prep: theta inverses + ws init ----
        int t = threadIdx.x;
        if (t < 48) {
            int m = t >> 4, b = t & 15;
            const float* th = (m == 0 ? sc : (m == 1 ? rot : tr)) + b * 6;
            float a  = th[0], bbv = th[1], tx = th[2];
            float c  = th[3], d   = th[4], ty = th[5];
            float L10 = c / a;
            float dp  = d  - L10 * bbv;
            float typ = ty - L10 * tx;
            float i10 = (0.0f - L10) / dp;
            float i00 = (1.0f - bbv * i10) / a;
            float i11 = 1.0f / dp;
            float i01 = (0.0f - bbv * i11) / a;
            float i12 = (0.0f - typ) / dp;
            float i02 = (0.0f - bbv * i12 - tx) / a;
            float* o = ws_inv + m * 96 + b * 6;
            o[0] = i00; o[1] = i01; o[2] = i02;
            o[3] = i10; o[4] = i11; o[5] = i12;
        }
        bbox[t] = ((t & 3) < 2) ? INT_MAX : INT_MIN;
        if (t == 0) *qcount = 0;
    }
}

// ---------------- LDS-tiled affine grid_sample (device body) ----------------
__device__ __forceinline__ void gsample_tile(const float* __restrict__ src,
                                             float* __restrict__ dst,
                                             float* __restrict__ dst2,
                                             const float* __restrict__ thetas,
                                             int b, int tile, float* tb) {
    int ox = (tile & 15) * 32, oy = (tile >> 4) * 32;
    const float* th = thetas + b * 6;
    float t0 = th[0], t1 = th[1], t2 = th[2], t3 = th[3], t4 = th[4], t5 = th[5];
    const float* im = src + (size_t)b * NPIX;

    float sxmin = 1e30f, sxmax = -1e30f, symin = 1e30f, symax = -1e30f;
    #pragma unroll
    for (int cy = 0; cy < 2; ++cy)
        #pragma unroll
        for (int cx = 0; cx < 2; ++cx) {
            float X = (2.0f * (float)(ox + cx * 31) + 1.0f) / 512.0f - 1.0f;
            float Y = (2.0f * (float)(oy + cy * 31) + 1.0f) / 512.0f - 1.0f;
            float gx = t0 * X + t1 * Y + t2;
            float gy = t3 * X + t4 * Y + t5;
            float sx = ((gx + 1.0f) * 512.0f - 1.0f) * 0.5f;
            float sy = ((gy + 1.0f) * 512.0f - 1.0f) * 0.5f;
            sxmin = fminf(sxmin, sx); sxmax = fmaxf(sxmax, sx);
            symin = fminf(symin, sy); symax = fmaxf(symax, sy);
        }
    int rx0 = (int)floorf(sxmin) - 1;
    int ry0 = (int)floorf(symin) - 1;
    bool fits = ((int)floorf(sxmax) + 2 - rx0 < GTS) &&
                ((int)floorf(symax) + 2 - ry0 < GTS);

    int t = threadIdx.x;
    int py = oy + (t >> 3);
    int px0 = ox + (t & 7) * 4;
    float Y = (2.0f * (float)py + 1.0f) / 512.0f - 1.0f;
    float r[4];

    if (fits) {
        for (int i = t; i < GTS * GTS; i += 256) {
            int rr = i / GTS, cc = i - rr * GTS;
            int gy_ = ry0 + rr, gx_ = rx0 + cc;
            float v = 0.0f;
            if (gx_ >= 0 && gx_ < 512 && gy_ >= 0 && gy_ < 512)
                v = im[gy_ * 512 + gx_];
            tb[rr * GSTR + cc] = v;
        }
        __syncthreads();
        #pragma unroll
        for (int k = 0; k < 4; ++k) {
            float X = (2.0f * (float)(px0 + k) + 1.0f) / 512.0f - 1.0f;
            float gx = t0 * X + t1 * Y + t2;
            float gy = t3 * X + t4 * Y + t5;
            float x = ((gx + 1.0f) * 512.0f - 1.0f) * 0.5f;
            float y = ((gy + 1.0f) * 512.0f - 1.0f) * 0.5f;
            float xf = floorf(x), yf = floorf(y);
            int ix = (int)xf, iy = (int)yf;
            float wx = x - xf, wy = y - yf;
            int lx = ix - rx0, ly = iy - ry0;
            float v;
            v  = tb[ly * GSTR + lx]           * ((1.0f - wx) * (1.0f - wy));
            v += tb[ly * GSTR + lx + 1]       * (wx * (1.0f - wy));
            v += tb[(ly + 1) * GSTR + lx]     * ((1.0f - wx) * wy);
            v += tb[(ly + 1) * GSTR + lx + 1] * (wx * wy);
            r[k] = v;
        }
    } else {
        #pragma unroll
        for (int k = 0; k < 4; ++k) {
            float X = (2.0f * (float)(px0 + k) + 1.0f) / 512.0f - 1.0f;
            float gx = t0 * X + t1 * Y + t2;
            float gy = t3 * X + t4 * Y + t5;
            r[k] = gs_bilinear(im, 512, 512, gx, gy);
        }
    }
    float4 v4 = make_float4(r[0], r[1], r[2], r[3]);
    size_t op = (size_t)b * NPIX + py * 512 + px0;
    *(float4*)(dst + op) = v4;
    if (dst2) *(float4*)(dst2 + op) = v4;
}

// stage 2: gsample g3 + otile classification (live tiles -> queue + byte map)
__global__ void __launch_bounds__(256) k_g3ot(const float* __restrict__ src,
                                              float* __restrict__ dst,
                                              const float* __restrict__ inv3,
                                              const unsigned* __restrict__ occ,
                                              const float* __restrict__ inv1,
                                              const float* __restrict__ inv2,
                                              unsigned char* __restrict__ otile,
                                              int* __restrict__ queue,
                                              int* __restrict__ qcount) {
    __shared__ float tb[GTS * GSTR];
    int bid = blockIdx.x;
    if (bid < 4096) {
        gsample_tile(src, dst, nullptr, inv3, bid >> 8, bid & 255, tb);
        return;
    }
    int idx = (bid - 4096) * 256 + threadIdx.x;   // 0..65535
    int jb = idx >> 10, tile = idx & 1023;
    int j = jb >> 4, b = jb & 15;
    int ty = tile >> 5, tx = tile & 31;
    const float* t1 = inv1 + b * 6;
    const float* t2 = inv2 + b * 6;
    float xs[2] = { (float)(tx * 16), (float)(tx * 16 + 15) };
    float ys[2] = { (float)(ty * 16), (float)(ty * 16 + 15) };
    float sxmin = 1e30f, sxmax = -1e30f, symin = 1e30f, symax = -1e30f;
    for (int cy = 0; cy < 2; ++cy)
        for (int cx = 0; cx < 2; ++cx) {
            float X = (2.0f * xs[cx] + 1.0f) / 512.0f - 1.0f;
            float Y = (2.0f * ys[cy] + 1.0f) / 512.0f - 1.0f;
            float gx = t1[0] * X + t1[1] * Y + t1[2];
            float gy = t1[3] * X + t1[4] * Y + t1[5];
            float sx = ((gx + 1.0f) * 512.0f - 1.0f) * 0.5f;
            float sy = ((gy + 1.0f) * 512.0f - 1.0f) * 0.5f;
            sxmin = fminf(sxmin, sx); sxmax = fmaxf(sxmax, sx);
            symin = fminf(symin, sy); symax = fmaxf(symax, sy);
        }
    int c0 = max((int)floorf(sxmin) - 1, 0), c1 = min((int)floorf(sxmax) + 2, 511);
    int r0 = max((int)floorf(symin) - 1, 0), r1 = min((int)floorf(symax) + 2, 511);
    bool any = false;
    if (c0 <= c1 && r0 <= r1) {
        float A0 = t2[0], A1 = t2[1], A3 = t2[3], A4 = t2[4];
        float Kx = 0.5f * (-511.0f * (A0 + A1) + 512.0f * t2[2] + 511.0f);
        float Ky = 0.5f * (-511.0f * (A3 + A4) + 512.0f * t2[5] + 511.0f);
        float pxmin = A0 * (A0 >= 0.f ? c0 : c1) + A1 * (A1 >= 0.f ? r0 : r1) + Kx;
        float pxmax = A0 * (A0 >= 0.f ? c1 : c0) + A1 * (A1 >= 0.f ? r1 : r0) + Kx;
        float pymin = A3 * (A3 >= 0.f ? c0 : c1) + A4 * (A4 >= 0.f ? r0 : r1) + Ky;
        float pymax = A3 * (A3 >= 0.f ? c1 : c0) + A4 * (A4 >= 0.f ? r1 : r0) + Ky;
        int xlo = max((int)floorf(pxmin) - 1, 0), xhi = min((int)floorf(pxmax) + 2, 511);
        int ylo = max((int)floorf(pymin) - 1, 0), yhi = min((int)floorf(pymax) + 2, 511);
        if (xlo <= xhi && ylo <= yhi)
            for (int tr = ylo >> 4; tr <= yhi >> 4; ++tr)
                for (int tc = xlo >> 4; tc <= xhi >> 4; ++tc)
                    if ((occ[j * 32 + tr] >> tc) & 1u) any = true;
    }
    otile[idx] = any ? 1 : 0;
    if (any) {
        int pos = atomicAdd(qcount, 1);
        queue[pos] = (jb << 10) | tile;   // disjoint writes; order irrelevant
    }
}

// stages 3/4: plain tiled gsample passes
__global__ void __launch_bounds__(256) k_gsample(const float* __restrict__ src,
                                                 float* __restrict__ dst,
                                                 float* __restrict__ dst2,
                                                 const float* __restrict__ thetas) {
    __shared__ float tb[GTS * GSTR];
    gsample_tile(src, dst, dst2, thetas, blockIdx.x >> 8, blockIdx.x & 255, tb);
}

__device__ __forceinline__ float rm2_val(const float* mk, const float* t2, int cx_, int ry_) {
    float X2 = (2.0f * (float)cx_ + 1.0f) / 512.0f - 1.0f;
    float Y2 = (2.0f * (float)ry_ + 1.0f) / 512.0f - 1.0f;
    float g2x = t2[0] * X2 + t2[1] * Y2 + t2[2];
    float g2y = t2[3] * X2 + t2[4] * Y2 + t2[5];
    return gs_bilinear(mk, 512, 512, g2x, g2y);
}

// stage 5: masked zero-fill of dead tiles + mask chain on live tiles (disjoint writes)
// blocks [0,2048): zero dead float4s; [2048,3072): queue consumer
__global__ void __launch_bounds__(256) k_zml(const float* __restrict__ masks,
                                             float* __restrict__ out3,
                                             const float* __restrict__ inv1,
                                             const float* __restrict__ inv2,
                                             const unsigned char* __restrict__ otile,
                                             const int* __restrict__ queue,
                                             const int* __restrict__ qcount,
                                             int* __restrict__ bbox) {
    int bid = blockIdx.x;
    if (bid < 2048) {
        const float4 z4 = make_float4(0.f, 0.f, 0.f, 0.f);
        float4* p = (float4*)out3;
        int stride = 2048 * 256;
        for (int i = bid * 256 + threadIdx.x; i < 64 * NPIX / 4; i += stride) {
            int jb = i >> 16;             // 65536 float4 per (j,b) image
            int w = i & 65535;
            int y = w >> 7;               // (w*4)>>9
            int x = (w << 2) & 511;
            int tile = ((y >> 4) << 5) | (x >> 4);   // float4 never spans tiles (4|x)
            if (!otile[(jb << 10) | tile]) p[i] = z4;
        }
        return;
    }
    __shared__ int sbb[4];
    int n = *qcount;
    for (int q = bid - 2048; q < n; q += 1024) {
        int e = queue[q];
        int jb = e >> 10, tile = e & 1023;
        if (threadIdx.x == 0) { sbb[0] = INT_MAX; sbb[1] = INT_MAX; sbb[2] = INT_MIN; sbb[3] = INT_MIN; }
        __syncthreads();

        int ty = tile >> 5, tx = tile & 31;
        int y = ty * 16 + (threadIdx.x >> 4);
        int x = tx * 16 + (threadIdx.x & 15);
        int j = jb >> 4, b = jb & 15;
        const float* t1 = inv1 + b * 6;
        const float* t2 = inv2 + b * 6;
        const float* mk = masks + (size_t)j * NPIX;

        float X = (2.0f * (float)x + 1.0f) / 512.0f - 1.0f;
        float Y = (2.0f * (float)y + 1.0f) / 512.0f - 1.0f;
        float gx = t1[0] * X + t1[1] * Y + t1[2];
        float gy = t1[3] * X + t1[4] * Y + t1[5];
        float sx = ((gx + 1.0f) * 512.0f - 1.0f) * 0.5f;
        float sy = ((gy + 1.0f) * 512.0f - 1.0f) * 0.5f;
        float xf = floorf(sx), yf = floorf(sy);
        int ix = (int)xf, iy = (int)yf;
        float wx = sx - xf, wy = sy - yf;

        float v = 0.0f;
        bool vx0 = (ix >= 0) && (ix < 512);
        bool vx1 = (ix >= -1) && (ix < 511);
        bool vy0 = (iy >= 0) && (iy < 512);
        bool vy1 = (iy >= -1) && (iy < 511);
        if (vx0 && vy0) v += rm2_val(mk, t2, ix,     iy    ) * ((1.0f - wx) * (1.0f - wy));
        if (vx1 && vy0) v += rm2_val(mk, t2, ix + 1, iy    ) * (wx * (1.0f - wy));
        if (vx0 && vy1) v += rm2_val(mk, t2, ix,     iy + 1) * ((1.0f - wx) * wy);
        if (vx1 && vy1) v += rm2_val(mk, t2, ix + 1, iy + 1) * (wx * wy);

        float res = 0.0f;
        if (v >= 0.5f) {
            res = 1.0f;
            atomicMin(&sbb[0], y); atomicMin(&sbb[1], x);
            atomicMax(&sbb[2], y); atomicMax(&sbb[3], x);
        }
        out3[(size_t)jb * NPIX + y * 512 + x] = res;

        __syncthreads();
        if (threadIdx.x == 0 && sbb[2] != INT_MIN) {
            atomicMin(&bbox[jb * 4 + 0], sbb[0]);
            atomicMin(&bbox[jb * 4 + 1], sbb[1]);
            atomicMax(&bbox[jb * 4 + 2], sbb[2]);
            atomicMax(&bbox[jb * 4 + 3], sbb[3]);
        }
        __syncthreads();
    }
}

// stage 6: fused COM stats -> crop origins
__global__ void __launch_bounds__(256) k_stats(const float* __restrict__ pred,
                                               const float* __restrict__ mrot,
                                               const int* __restrict__ bbox,
                                               int* __restrict__ xy) {
    int jb = blockIdx.x;
    int b = jb & 15;
    int rmin = bbox[jb*4+0], cmin = bbox[jb*4+1], rmax = bbox[jb*4+2], cmax = bbox[jb*4+3];
    const float* img = pred + (size_t)b * NPIX;
    const float* mk  = mrot + (size_t)jb * NPIX;
    int lane = threadIdx.x & 63, w = threadIdx.x >> 6;
    int W = cmax - cmin + 1;
    int total = (rmax >= rmin) ? W * (rmax - rmin + 1) : 0;

    double msum = 0.0, isum = 0.0;
    for (int i = threadIdx.x; i < total; i += 256) {
        int r = rmin + i / W, c = cmin + i % W;
        float m = mk[r * 512 + c];
        if (m != 0.0f) {
            msum += (double)m;
            isum += (double)(img[r * 512 + c] * m);
        }
    }
    for (int o = 32; o > 0; o >>= 1) {
        msum += __shfl_down(msum, o, 64);
        isum += __shfl_down(isum, o, 64);
    }
    __shared__ double s0[4], s1[4], s2[4];
    __shared__ double sthr;
    if (lane == 0) { s0[w] = msum; s1[w] = isum; }
    __syncthreads();
    if (threadIdx.x == 0) {
        double M = s0[0] + s0[1] + s0[2] + s0[3];
        double I = s1[0] + s1[1] + s1[2] + s1[3];
        sthr = (I / fmax(M, 1.0)) * 1.5;
    }
    __syncthreads();
    double t = sthr;

    double wsum = 0.0, sy = 0.0, sx = 0.0;
    for (int i = threadIdx.x; i < total; i += 256) {
        int r = rmin + i / W, c = cmin + i % W;
        float m = mk[r * 512 + c];
        if (m != 0.0f) {
            float v = img[r * 512 + c] * m;
            if ((double)v > t) {
                double vd = (double)v;
                wsum += vd;
                sy += vd * (double)r;
                sx += vd * (double)c;
            }
        }
    }
    for (int o = 32; o > 0; o >>= 1) {
        wsum += __shfl_down(wsum, o, 64);
        sy   += __shfl_down(sy,   o, 64);
        sx   += __shfl_down(sx,   o, 64);
    }
    __syncthreads();
    if (lane == 0) { s0[w] = wsum; s1[w] = sy; s2[w] = sx; }
    __syncthreads();
    if (threadIdx.x == 0) {
        double W_ = s0[0] + s0[1] + s0[2] + s0[3];
        double SY = s1[0] + s1[1] + s1[2] + s1[3];
        double SX = s2[0] + s2[1] + s2[2] + s2[3];
        double tot = W_ + 1e-8;
        int x0 = (int)rint(SY / tot) - RAD;
        int y0 = (int)rint(SX / tot) - RAD;
        x0 = min(max(x0, 0), 512 - DSZ);
        y0 = min(max(y0, 0), 512 - DSZ);
        xy[jb * 2 + 0] = x0;
        xy[jb * 2 + 1] = y0;
    }
}

// one patch pass: crop->dot divide->grid_sample->write back (LDS stride PSTR)
__device__ __forceinline__ void patch_one(float* __restrict__ im, float* __restrict__ patch,
                                          int x0, int y0, float a,
                                          float t0, float t1, float t2,
                                          float t3, float t4, float t5) {
    for (int t = threadIdx.x; t < DSZ * DSZ; t += 1024) {
        int u = t / DSZ, v = t % DSZ;
        float val = im[(x0 + u) * 512 + (y0 + v)];
        int du = u - RAD, dv = v - RAD;
        if (du * du + dv * dv <= 16) val = val / a;
        patch[u * PSTR + v] = val;
    }
    __syncthreads();
    for (int t = threadIdx.x; t < DSZ * DSZ; t += 1024) {
        int py = t / DSZ, px = t % DSZ;
        float X = (2.0f * (float)px + 1.0f) / 120.0f - 1.0f;
        float Y = (2.0f * (float)py + 1.0f) / 120.0f - 1.0f;
        float gx = t0 * X + t1 * Y + t2;
        float gy = t3 * X + t4 * Y + t5;
        float o = gs_bilinear_patch(patch, gx, gy);
        im[(x0 + py) * 512 + (y0 + px)] = o;
    }
}

// stage 7: revise. One block per (b,j); parallel when rects disjoint,
// deterministic sequential fallback when any same-b rects overlap.
__global__ void __launch_bounds__(1024) k_patch(float* __restrict__ img,
                                                const int* __restrict__ xy,
                                                const float* __restrict__ inv1,
                                                const float* __restrict__ adj) {
    __shared__ float patch[DSZ * PSTR];
    int b = blockIdx.x >> 2, j = blockIdx.x & 3;
    int rx[4], ry[4];
    #pragma unroll
    for (int k = 0; k < 4; ++k) {
        rx[k] = xy[(k * 16 + b) * 2 + 0];
        ry[k] = xy[(k * 16 + b) * 2 + 1];
    }
    bool overlap = false;
    #pragma unroll
    for (int i = 0; i < 4; ++i)
        #pragma unroll
        for (int k = 0; k < 4; ++k)
            if (i < k && abs(rx[i] - rx[k]) < DSZ && abs(ry[i] - ry[k]) < DSZ)
                overlap = true;

    float a = adj[b];
    float* im = img + (size_t)b * NPIX;
    const float* th = inv1 + b * 6;
    float t0 = th[0], t1 = th[1], t2 = th[2], t3 = th[3], t4 = th[4], t5 = th[5];

    if (!overlap) {
        patch_one(im, patch, rx[j], ry[j], a, t0, t1, t2, t3, t4, t5);
    } else {
        if (j != 0) return;
        for (int jj = 0; jj < 4; ++jj) {
            patch_one(im, patch, rx[jj], ry[jj], a, t0, t1, t2, t3, t4, t5);
            __threadfence_block();
            __syncthreads();
        }
    }
}

// ---------------- launcher ----------------

extern "C" void kernel_launch(void* const* d_in, const int* in_sizes, int n_in,
                              void* d_out, int out_size, void* d_ws, size_t ws_size,
                              hipStream_t stream) {
    const float* base  = (const float*)d_in[0];
    const float* sc    = (const float*)d_in[1];
    const float* rot   = (const float*)d_in[2];
    const float* tr    = (const float*)d_in[3];
    const float* adj   = (const float*)d_in[4];
    const float* masks = (const float*)d_in[5];

    float* out  = (float*)d_out;
    float* out0 = out;                               // base_inp
    float* out1 = out0 + (size_t)NB * NPIX;          // pred_input
    float* out2 = out1 + (size_t)NB * NPIX;          // pred_revise
    float* out3 = out2 + (size_t)NB * NPIX;          // masks_rot (4,16,512,512)

    // ws layout (bytes): inv @0, xy @4096, bbox @8192, occ @12288,
    //                    qcount @16128, otile @16384 (64KB), queue @81920 (256KB)
    float*         inv1   = (float*)d_ws;
    float*         inv2   = inv1 + 96;
    float*         inv3   = inv1 + 192;
    int*           xy     = (int*)((char*)d_ws + 4096);
    int*           bbox   = (int*)((char*)d_ws + 8192);
    unsigned*      occ    = (unsigned*)((char*)d_ws + 12288);
    int*           qcount = (int*)((char*)d_ws + 16128);
    unsigned char* otile  = (unsigned char*)((char*)d_ws + 16384);
    int*           queue  = (int*)((char*)d_ws + 81920);

    // 1: prep + occ + upsample (independent)
    k_init<<<4129, 256, 0, stream>>>(base, sc, rot, tr, masks, out0,
                                     (float*)d_ws, bbox, occ, qcount);
    // 2: g3 (out0 -> out2) + otile
    k_g3ot<<<4352, 256, 0, stream>>>(out0, out2, inv3, occ, inv1, inv2,
                                     otile, queue, qcount);
    // 3: g2 (out2 -> out3[:16] temp)
    k_gsample<<<4096, 256, 0, stream>>>(out2, out3, nullptr, inv2);
    // 4: g1 (temp -> out1, dual-store revise seed into out2)
    k_gsample<<<4096, 256, 0, stream>>>(out3, out1, out2, inv1);
    // 5: masked zero of dead tiles + mask chain on live tiles (disjoint writes)
    k_zml<<<3072, 256, 0, stream>>>(masks, out3, inv1, inv2, otile, queue, qcount, bbox);
    // 6: COM stats over per-(j,b) bounding boxes
    k_stats<<<64, 256, 0, stream>>>(out1, out3, bbox, xy);
    // 7: revise
    k_patch<<<64, 1024, 0, stream>>>(out2, xy, inv1, adj);
}